// Round 3
// baseline (489.825 us; speedup 1.0000x reference)
//
#include <hip/hip_runtime.h>

typedef __bf16 bf16_t;
typedef __bf16 bf16x8 __attribute__((ext_vector_type(8)));
typedef float floatx4 __attribute__((ext_vector_type(4)));

#define MFMA16(a, b, c) __builtin_amdgcn_mfma_f32_16x16x32_bf16(a, b, c, 0, 0, 0)

#define AS1 __attribute__((address_space(1)))
#define AS3 __attribute__((address_space(3)))

// async 16B global -> LDS (lane i lands at ldsbase + i*16; ldsbase wave-uniform)
__device__ __forceinline__ void gload_lds16(const bf16_t* g, bf16_t* l) {
    __builtin_amdgcn_global_load_lds((const AS1 unsigned int*)g,
                                     (AS3 unsigned int*)l, 16, 0, 0);
}

struct TPtrs { const void* src[5]; bf16_t* dst[5]; };
struct GPtrs { const bf16_t* Bt[4]; bf16_t* C[4]; };

// ---------------------------------------------------------------------------
// Detect input dtype on-device (flag=1 -> bf16 inputs; measured: fp32 world).
// ---------------------------------------------------------------------------
__global__ __launch_bounds__(256) void detect_dtype_kernel(const unsigned int* W,
                                                           int* flag) {
    int tid = threadIdx.x;
    int cnt = 0;
    for (int i = tid; i < 4096; i += 256) {
        unsigned int fb = (W[i] & 0xFFFFu) << 16;
        float v = __uint_as_float(fb);
        float a = fabsf(v);
        if (a > 1e-5f && a < 4.f) cnt++;
    }
    __shared__ int s[256];
    s[tid] = cnt;
    __syncthreads();
    for (int st = 128; st > 0; st >>= 1) {
        if (tid < st) s[tid] += s[tid + st];
        __syncthreads();
    }
    if (tid == 0) *flag = (s[0] > 2048) ? 1 : 0;
}

// ---------------------------------------------------------------------------
// Canonicalize x -> bf16. 8,388,608 elems, 8/thread, grid 4096.
// ---------------------------------------------------------------------------
__global__ __launch_bounds__(256) void convert_x_kernel(const void* __restrict__ src,
                                                        bf16_t* __restrict__ dst,
                                                        const int* __restrict__ flag) {
    size_t i0 = ((size_t)blockIdx.x * 256 + threadIdx.x) * 8;
    bf16x8 o;
    if (*flag) {
        o = *(const bf16x8*)((const bf16_t*)src + i0);
    } else {
        const float* s = (const float*)src + i0;
        float4 a = *(const float4*)s;
        float4 b = *(const float4*)(s + 4);
        o[0] = (bf16_t)a.x; o[1] = (bf16_t)a.y; o[2] = (bf16_t)a.z; o[3] = (bf16_t)a.w;
        o[4] = (bf16_t)b.x; o[5] = (bf16_t)b.y; o[6] = (bf16_t)b.z; o[7] = (bf16_t)b.w;
    }
    *(bf16x8*)(dst + i0) = o;
}

// ---------------------------------------------------------------------------
// Transpose 2048x2048 -> bf16: dst[n][k] = (bf16)src[k][n]. grid (32,32,5).
// ---------------------------------------------------------------------------
__global__ __launch_bounds__(256) void transpose_k(TPtrs p, const int* __restrict__ flag) {
    __shared__ bf16_t tile[64][72];  // +8 pad
    int z = blockIdx.z;
    bf16_t* dst = p.dst[z];
    int bx = blockIdx.x, by = blockIdx.y;
    int tid = threadIdx.x;
    int isbf = *flag;
#pragma unroll
    for (int l = 0; l < 2; ++l) {
        int idx = tid + 256 * l;          // 512 x 8 elems = 64 rows x 64 cols
        int r = idx >> 3, c8 = (idx & 7) * 8;
        bf16x8 o;
        if (isbf) {
            const bf16_t* src = (const bf16_t*)p.src[z];
            o = *(const bf16x8*)&src[(size_t)(by * 64 + r) * 2048 + bx * 64 + c8];
        } else {
            const float* src = (const float*)p.src[z];
            const float* sp = &src[(size_t)(by * 64 + r) * 2048 + bx * 64 + c8];
            float4 a = *(const float4*)sp;
            float4 b = *(const float4*)(sp + 4);
            o[0] = (bf16_t)a.x; o[1] = (bf16_t)a.y; o[2] = (bf16_t)a.z; o[3] = (bf16_t)a.w;
            o[4] = (bf16_t)b.x; o[5] = (bf16_t)b.y; o[6] = (bf16_t)b.z; o[7] = (bf16_t)b.w;
        }
        *(bf16x8*)&tile[r][c8] = o;
    }
    __syncthreads();
#pragma unroll
    for (int l = 0; l < 2; ++l) {
        int idx = tid + 256 * l;
        int r = idx >> 3, c8 = (idx & 7) * 8;
        bf16x8 o;
#pragma unroll
        for (int m = 0; m < 8; ++m) o[m] = tile[c8 + m][r];
        *(bf16x8*)&dst[(size_t)(bx * 64 + r) * 2048 + by * 64 + c8] = o;
    }
}

// ---------------------------------------------------------------------------
// GEMM  C[M,N] = A[M,K] @ Bt[N,K]^T, bf16 out.  m97 structure:
// BM=BN=128, BK=64, 4 waves, global_load_lds width=16, UNPADDED LDS.
// blockIdx.z selects Bt/C pair (QKVG fused launch).
// ---------------------------------------------------------------------------
__global__ __launch_bounds__(256) void gemm_bt(const bf16_t* __restrict__ A, GPtrs p,
                                               int K) {
    __shared__ bf16_t sA[128 * 64];
    __shared__ bf16_t sB[128 * 64];
    const bf16_t* __restrict__ Bt = p.Bt[blockIdx.z];
    bf16_t* __restrict__ C = p.C[blockIdx.z];
    const int N = 2048;
    int tid = threadIdx.x, lane = tid & 63, wid = tid >> 6;
    int l15 = lane & 15, quad = lane >> 4;
    int wm = wid >> 1, wn = wid & 1;
    int m0 = blockIdx.y * 128, n0 = blockIdx.x * 128;

    // staging geometry: idx = l*256 + tid; row = idx>>3; col8 = (idx&7)*8;
    // LDS elem offset = idx*8  (lane-order contiguous, matches HW scatter)
    int sidx = tid;                 // l=0 idx
    int srow = sidx >> 3, sc8 = (sidx & 7) * 8;
    const bf16_t* ga = &A[(size_t)(m0 + srow) * K + sc8];
    const bf16_t* gb = &Bt[(size_t)(n0 + srow) * K + sc8];
    bf16_t* la = &sA[(size_t)(wid * 64) * 8];
    bf16_t* lb = &sB[(size_t)(wid * 64) * 8];
    const size_t rstep = (size_t)32 * K;      // 256 threads / 8 per row

    floatx4 acc[4][4] = {};
    for (int kk = 0; kk < K; kk += 64) {
#pragma unroll
        for (int l = 0; l < 4; ++l)
            gload_lds16(ga + l * rstep + kk, la + l * 2048);
#pragma unroll
        for (int l = 0; l < 4; ++l)
            gload_lds16(gb + l * rstep + kk, lb + l * 2048);
        __syncthreads();
#pragma unroll
        for (int k2 = 0; k2 < 2; ++k2) {
            int koff = k2 * 32 + quad * 8;
            bf16x8 af[4], bfv[4];
#pragma unroll
            for (int i = 0; i < 4; ++i)
                af[i] = *(const bf16x8*)&sA[(wm * 64 + i * 16 + l15) * 64 + koff];
#pragma unroll
            for (int j = 0; j < 4; ++j)
                bfv[j] = *(const bf16x8*)&sB[(wn * 64 + j * 16 + l15) * 64 + koff];
#pragma unroll
            for (int i = 0; i < 4; ++i)
#pragma unroll
                for (int j = 0; j < 4; ++j)
                    acc[i][j] = MFMA16(af[i], bfv[j], acc[i][j]);
        }
        __syncthreads();
    }
#pragma unroll
    for (int i = 0; i < 4; ++i)
#pragma unroll
        for (int j = 0; j < 4; ++j)
#pragma unroll
            for (int r = 0; r < 4; ++r) {
                int row = m0 + wm * 64 + i * 16 + quad * 4 + r;
                int col = n0 + wn * 64 + j * 16 + l15;
                C[(size_t)row * N + col] = (bf16_t)acc[i][j][r];
            }
}

// ---------------------------------------------------------------------------
// Final GEMM: out dtype dynamic (flag=1 -> bf16, else fp32).  m97 structure.
// ---------------------------------------------------------------------------
__global__ __launch_bounds__(256) void gemm_bt_dyn(const bf16_t* __restrict__ A,
                                                   const bf16_t* __restrict__ Bt,
                                                   void* __restrict__ C, int K,
                                                   const int* __restrict__ flag) {
    __shared__ bf16_t sA[128 * 64];
    __shared__ bf16_t sB[128 * 64];
    const int N = 2048;
    int tid = threadIdx.x, lane = tid & 63, wid = tid >> 6;
    int l15 = lane & 15, quad = lane >> 4;
    int wm = wid >> 1, wn = wid & 1;
    int m0 = blockIdx.y * 128, n0 = blockIdx.x * 128;
    int isbf = *flag;

    int srow = tid >> 3, sc8 = (tid & 7) * 8;
    const bf16_t* ga = &A[(size_t)(m0 + srow) * K + sc8];
    const bf16_t* gb = &Bt[(size_t)(n0 + srow) * K + sc8];
    bf16_t* la = &sA[(size_t)(wid * 64) * 8];
    bf16_t* lb = &sB[(size_t)(wid * 64) * 8];
    const size_t rstep = (size_t)32 * K;

    floatx4 acc[4][4] = {};
    for (int kk = 0; kk < K; kk += 64) {
#pragma unroll
        for (int l = 0; l < 4; ++l)
            gload_lds16(ga + l * rstep + kk, la + l * 2048);
#pragma unroll
        for (int l = 0; l < 4; ++l)
            gload_lds16(gb + l * rstep + kk, lb + l * 2048);
        __syncthreads();
#pragma unroll
        for (int k2 = 0; k2 < 2; ++k2) {
            int koff = k2 * 32 + quad * 8;
            bf16x8 af[4], bfv[4];
#pragma unroll
            for (int i = 0; i < 4; ++i)
                af[i] = *(const bf16x8*)&sA[(wm * 64 + i * 16 + l15) * 64 + koff];
#pragma unroll
            for (int j = 0; j < 4; ++j)
                bfv[j] = *(const bf16x8*)&sB[(wn * 64 + j * 16 + l15) * 64 + koff];
#pragma unroll
            for (int i = 0; i < 4; ++i)
#pragma unroll
                for (int j = 0; j < 4; ++j)
                    acc[i][j] = MFMA16(af[i], bfv[j], acc[i][j]);
        }
        __syncthreads();
    }
#pragma unroll
    for (int i = 0; i < 4; ++i)
#pragma unroll
        for (int j = 0; j < 4; ++j)
#pragma unroll
            for (int r = 0; r < 4; ++r) {
                int row = m0 + wm * 64 + i * 16 + quad * 4 + r;
                int col = n0 + wn * 64 + j * 16 + l15;
                if (isbf) ((bf16_t*)C)[(size_t)row * N + col] = (bf16_t)acc[i][j][r];
                else      ((float*)C)[(size_t)row * N + col] = acc[i][j][r];
            }
}

// ---------------------------------------------------------------------------
// RoPE (rotate-half, base 10000) in place on q and k; q also scaled.
// grid 32768: first half q, second half k.
// ---------------------------------------------------------------------------
__global__ __launch_bounds__(256) void rope_kernel(bf16_t* Q, bf16_t* Kb) {
    int isq = blockIdx.x < 16384;
    bf16_t* X = isq ? Q : Kb;
    float scale = isq ? 0.08838834764831845f : 1.0f;
    size_t gt = (size_t)(blockIdx.x & 16383) * 256 + threadIdx.x;
    int i = gt & 63;
    int h = (gt >> 6) & 15;
    int s = (gt >> 10) & 2047;
    int b = gt >> 21;
    size_t base = ((size_t)((b * 2048 + s) * 16 + h)) << 7;
    float inv = exp2f(-(float)i * (13.287712379549449f / 64.f));  // 10000^(-i/64)
    float ang = (float)s * inv;
    float sn, cs;
    sincosf(ang, &sn, &cs);
    float x1 = (float)X[base + i];
    float x2 = (float)X[base + 64 + i];
    X[base + i]      = (bf16_t)((x1 * cs - x2 * sn) * scale);
    X[base + 64 + i] = (bf16_t)((x2 * cs + x1 * sn) * scale);
}

// ---------------------------------------------------------------------------
// Pass A: Ut[e][d] = sum_t v[t][e] * gamma^(63-t) * k[t][d].  grid 1024.
// ---------------------------------------------------------------------------
__global__ __launch_bounds__(256) void chunk_state_kernel(const bf16_t* __restrict__ Kc,
                                                          const bf16_t* __restrict__ Vc,
                                                          bf16_t* __restrict__ U) {
    __shared__ bf16_t sKT[128][72];
    __shared__ bf16_t sVT[128][72];
    int bx = blockIdx.x;
    int n = bx & 31, h = (bx >> 5) & 15, b = bx >> 9;
    int tid = threadIdx.x, lane = tid & 63, wid = tid >> 6;
    int l15 = lane & 15, quad = lane >> 4;
    int wm = wid >> 1, wn = wid & 1;
    float log2g = log2f(1.f - exp2f(-5.f - (float)h));

#pragma unroll
    for (int l = 0; l < 4; ++l) {
        int idx = tid + 256 * l;          // 1024 = 64 rows x 16 vec8
        int t = idx >> 4, d8 = (idx & 15) * 8;
        size_t gb = (((size_t)((b * 2048 + n * 64 + t) * 16 + h)) << 7) + d8;
        bf16x8 kv = *(const bf16x8*)&Kc[gb];
        bf16x8 vv = *(const bf16x8*)&Vc[gb];
        float kdec = exp2f((float)(63 - t) * log2g);
#pragma unroll
        for (int m = 0; m < 8; ++m) {
            sKT[d8 + m][t] = (bf16_t)((float)kv[m] * kdec);
            sVT[d8 + m][t] = vv[m];
        }
    }
    __syncthreads();

    floatx4 acc[4][4] = {};
#pragma unroll
    for (int k2 = 0; k2 < 2; ++k2) {
        int t0 = k2 * 32 + quad * 8;
        bf16x8 af[4], bfv[4];
#pragma unroll
        for (int i = 0; i < 4; ++i) af[i] = *(const bf16x8*)&sVT[wm * 64 + i * 16 + l15][t0];
#pragma unroll
        for (int j = 0; j < 4; ++j) bfv[j] = *(const bf16x8*)&sKT[wn * 64 + j * 16 + l15][t0];
#pragma unroll
        for (int i = 0; i < 4; ++i)
#pragma unroll
            for (int j = 0; j < 4; ++j) acc[i][j] = MFMA16(af[i], bfv[j], acc[i][j]);
    }
    size_t ub = (size_t)bx * 16384;
#pragma unroll
    for (int i = 0; i < 4; ++i)
#pragma unroll
        for (int j = 0; j < 4; ++j)
#pragma unroll
            for (int r = 0; r < 4; ++r) {
                int e = wm * 64 + i * 16 + quad * 4 + r;
                int d = wn * 64 + j * 16 + l15;
                U[ub + (size_t)e * 128 + d] = (bf16_t)acc[i][j][r];
            }
}

// ---------------------------------------------------------------------------
// Pass B: in-place scan  St[n] = state before chunk n (transposed layout).
// ---------------------------------------------------------------------------
__global__ __launch_bounds__(256) void scan_kernel(bf16_t* __restrict__ US) {
    int bx = blockIdx.x;
    int bh = bx >> 3, slice = bx & 7;
    int h = bh & 15;
    float log2g = log2f(1.f - exp2f(-5.f - (float)h));
    float gC = exp2f(64.f * log2g);
    size_t base = (size_t)bh * 32 * 16384 + (size_t)slice * 2048 + (size_t)threadIdx.x * 8;
    float acc[8] = {};
    for (int n = 0; n < 32; ++n) {
        size_t o = base + (size_t)n * 16384;
        bf16x8 u = *(const bf16x8*)&US[o];
        bf16x8 s;
#pragma unroll
        for (int m = 0; m < 8; ++m) s[m] = (bf16_t)acc[m];
        *(bf16x8*)&US[o] = s;
#pragma unroll
        for (int m = 0; m < 8; ++m) acc[m] = gC * acc[m] + (float)u[m];
    }
}

// ---------------------------------------------------------------------------
// Pass C: chunk output + gated RMSNorm.  grid 1024.
// ---------------------------------------------------------------------------
__global__ __launch_bounds__(256) void chunk_out_kernel(
    const bf16_t* __restrict__ Q, const bf16_t* __restrict__ Kc,
    const bf16_t* __restrict__ Vc, const bf16_t* __restrict__ G,
    const void* __restrict__ gwp, const bf16_t* __restrict__ St,
    bf16_t* __restrict__ OG, const int* __restrict__ flag) {
    __shared__ bf16_t sQ[64][136];
    __shared__ bf16_t sK[64][136];
    __shared__ bf16_t sVT[128][72];
    __shared__ bf16_t sA[64][72];
    __shared__ float sgw[128];
    int bx = blockIdx.x;
    int n = bx & 31, h = (bx >> 5) & 15, b = bx >> 9;
    int tid = threadIdx.x, lane = tid & 63, wid = tid >> 6;
    int l15 = lane & 15, quad = lane >> 4;
    float log2g = log2f(1.f - exp2f(-5.f - (float)h));

    if (tid < 128) {
        sgw[tid] = (*flag) ? (float)((const bf16_t*)gwp)[tid] : ((const float*)gwp)[tid];
    }
#pragma unroll
    for (int l = 0; l < 4; ++l) {
        int idx = tid + 256 * l;
        int t = idx >> 4, d8 = (idx & 15) * 8;
        size_t gb = (((size_t)((b * 2048 + n * 64 + t) * 16 + h)) << 7) + d8;
        *(bf16x8*)&sQ[t][d8] = *(const bf16x8*)&Q[gb];
        *(bf16x8*)&sK[t][d8] = *(const bf16x8*)&Kc[gb];
        bf16x8 vv = *(const bf16x8*)&Vc[gb];
#pragma unroll
        for (int m = 0; m < 8; ++m) sVT[d8 + m][t] = vv[m];
    }
    __syncthreads();

    // ---- phase 1: A = q k^T (64x64), decay mask, stash bf16 in sA
    int t0 = wid * 16;
    floatx4 accA[4] = {};
#pragma unroll
    for (int kk = 0; kk < 4; ++kk) {
        int d0 = kk * 32 + quad * 8;
        bf16x8 aq = *(const bf16x8*)&sQ[t0 + l15][d0];
#pragma unroll
        for (int j = 0; j < 4; ++j) {
            bf16x8 bk = *(const bf16x8*)&sK[j * 16 + l15][d0];
            accA[j] = MFMA16(aq, bk, accA[j]);
        }
    }
#pragma unroll
    for (int j = 0; j < 4; ++j)
#pragma unroll
        for (int r = 0; r < 4; ++r) {
            int t = t0 + quad * 4 + r;
            int s = j * 16 + l15;
            int rel = t - s;
            float v = (rel >= 0) ? accA[j][r] * exp2f((float)rel * log2g) : 0.f;
            sA[t][s] = (bf16_t)v;
        }
    __syncthreads();

    // ---- phase 2: o = A v + (q*cross) S
    floatx4 acc[8] = {};
#pragma unroll
    for (int kk = 0; kk < 2; ++kk) {          // K = 64 (s)
        int s0 = kk * 32 + quad * 8;
        bf16x8 aa = *(const bf16x8*)&sA[t0 + l15][s0];
#pragma unroll
        for (int j = 0; j < 8; ++j) {
            bf16x8 bv = *(const bf16x8*)&sVT[j * 16 + l15][s0];
            acc[j] = MFMA16(aa, bv, acc[j]);
        }
    }
    size_t sb = (size_t)bx * 16384;
    float crossf = exp2f((float)(t0 + l15 + 1) * log2g);
#pragma unroll
    for (int kk = 0; kk < 4; ++kk) {          // K = 128 (d)
        int d0 = kk * 32 + quad * 8;
        bf16x8 aq = *(const bf16x8*)&sQ[t0 + l15][d0];
        bf16x8 aqs;
#pragma unroll
        for (int m = 0; m < 8; ++m) aqs[m] = (bf16_t)((float)aq[m] * crossf);
#pragma unroll
        for (int j = 0; j < 8; ++j) {
            bf16x8 bs = *(const bf16x8*)&St[sb + (size_t)(j * 16 + l15) * 128 + d0];
            acc[j] = MFMA16(aqs, bs, acc[j]);
        }
    }

    // ---- epilogue: gated RMSNorm per row t
#pragma unroll
    for (int r = 0; r < 4; ++r) {
        float ss = 0.f;
#pragma unroll
        for (int j = 0; j < 8; ++j) ss += acc[j][r] * acc[j][r];
        ss += __shfl_xor(ss, 1);
        ss += __shfl_xor(ss, 2);
        ss += __shfl_xor(ss, 4);
        ss += __shfl_xor(ss, 8);
        float rms = rsqrtf(ss * (1.f / 128.f) + 1e-5f);
        int t = t0 + quad * 4 + r;
        size_t gb = ((size_t)((b * 2048 + n * 64 + t) * 16 + h)) << 7;
#pragma unroll
        for (int j = 0; j < 8; ++j) {
            int e = j * 16 + l15;
            float g_ = (float)G[gb + e];
            float sw = g_ / (1.f + expf(-g_));
            OG[gb + e] = (bf16_t)(acc[j][r] * rms * sgw[e] * sw);
        }
    }
}

// ---------------------------------------------------------------------------
extern "C" void kernel_launch(void* const* d_in, const int* in_sizes, int n_in,
                              void* d_out, int out_size, void* d_ws, size_t ws_size,
                              hipStream_t stream) {
    char* ws = (char*)d_ws;
    const size_t WBYTES = 2048ull * 2048 * 2;   // 8 MiB per bf16 weight
    const size_t ABYTES = 4096ull * 2048 * 2;   // 16 MiB per bf16 activation
    int* flag = (int*)ws;
    char* base = ws + 256;
    bf16_t* xb = (bf16_t*)base;
    bf16_t* WT[5];
    for (int i = 0; i < 5; ++i) WT[i] = (bf16_t*)(base + ABYTES + i * WBYTES);
    char* act = base + ABYTES + 5 * WBYTES;
    bf16_t* qb = (bf16_t*)(act + 0 * ABYTES);
    bf16_t* kb = (bf16_t*)(act + 1 * ABYTES);
    bf16_t* vb = (bf16_t*)(act + 2 * ABYTES);
    bf16_t* gb = (bf16_t*)(act + 3 * ABYTES);
    bf16_t* og = (bf16_t*)(act + 4 * ABYTES);
    bf16_t* US = (bf16_t*)(act + 5 * ABYTES);  // 32 MiB

    // 0. detect dtype (flag=1 -> bf16 inputs)
    detect_dtype_kernel<<<1, 256, 0, stream>>>((const unsigned int*)d_in[1], flag);

    // 1. canonicalize x; transpose+canonicalize all 5 weights
    convert_x_kernel<<<4096, 256, 0, stream>>>(d_in[0], xb, flag);
    TPtrs tp;
    tp.src[0] = d_in[1]; tp.src[1] = d_in[2]; tp.src[2] = d_in[3];
    tp.src[3] = d_in[4]; tp.src[4] = d_in[6];
    for (int i = 0; i < 5; ++i) tp.dst[i] = WT[i];
    transpose_k<<<dim3(32, 32, 5), 256, 0, stream>>>(tp, flag);

    // 2. fused QKVG projections
    GPtrs gp;
    gp.Bt[0] = WT[0]; gp.Bt[1] = WT[1]; gp.Bt[2] = WT[2]; gp.Bt[3] = WT[3];
    gp.C[0] = qb; gp.C[1] = kb; gp.C[2] = vb; gp.C[3] = gb;
    gemm_bt<<<dim3(16, 32, 4), 256, 0, stream>>>(xb, gp, 2048);

    // 3. RoPE (q scaled by DK^-0.5) — q and k in one dispatch
    rope_kernel<<<32768, 256, 0, stream>>>(qb, kb);

    // 4. retention
    chunk_state_kernel<<<1024, 256, 0, stream>>>(kb, vb, US);
    scan_kernel<<<256, 256, 0, stream>>>(US);
    chunk_out_kernel<<<1024, 256, 0, stream>>>(qb, kb, vb, gb, d_in[5], US, og, flag);

    // 5. output projection (dtype-dynamic store)
    gemm_bt_dyn<<<dim3(16, 32, 1), 256, 0, stream>>>(og, WT[4], d_out, 2048, flag);
}

// Round 4
// 446.229 us; speedup vs baseline: 1.0977x; 1.0977x over previous
//
#include <hip/hip_runtime.h>

typedef __bf16 bf16_t;
typedef __bf16 bf16x8 __attribute__((ext_vector_type(8)));
typedef float floatx4 __attribute__((ext_vector_type(4)));

#define MFMA16(a, b, c) __builtin_amdgcn_mfma_f32_16x16x32_bf16(a, b, c, 0, 0, 0)

#define AS1 __attribute__((address_space(1)))
#define AS3 __attribute__((address_space(3)))

// async 16B global -> LDS (lane i lands at ldsbase + i*16; ldsbase wave-uniform)
__device__ __forceinline__ void gload_lds16(const bf16_t* g, bf16_t* l) {
    __builtin_amdgcn_global_load_lds((const AS1 unsigned int*)g,
                                     (AS3 unsigned int*)l, 16, 0, 0);
}

struct TPtrs { const void* src[5]; bf16_t* dst[5]; };
struct GPtrs { const bf16_t* Bt[4]; bf16_t* C[4]; };

// ---------------------------------------------------------------------------
// Detect input dtype on-device (flag=1 -> bf16 inputs; measured: fp32 world).
// ---------------------------------------------------------------------------
__global__ __launch_bounds__(256) void detect_dtype_kernel(const unsigned int* W,
                                                           int* flag) {
    int tid = threadIdx.x;
    int cnt = 0;
    for (int i = tid; i < 4096; i += 256) {
        unsigned int fb = (W[i] & 0xFFFFu) << 16;
        float v = __uint_as_float(fb);
        float a = fabsf(v);
        if (a > 1e-5f && a < 4.f) cnt++;
    }
    __shared__ int s[256];
    s[tid] = cnt;
    __syncthreads();
    for (int st = 128; st > 0; st >>= 1) {
        if (tid < st) s[tid] += s[tid + st];
        __syncthreads();
    }
    if (tid == 0) *flag = (s[0] > 2048) ? 1 : 0;
}

// ---------------------------------------------------------------------------
// Canonicalize x -> bf16. 8,388,608 elems, 8/thread, grid 4096.
// ---------------------------------------------------------------------------
__global__ __launch_bounds__(256) void convert_x_kernel(const void* __restrict__ src,
                                                        bf16_t* __restrict__ dst,
                                                        const int* __restrict__ flag) {
    size_t i0 = ((size_t)blockIdx.x * 256 + threadIdx.x) * 8;
    bf16x8 o;
    if (*flag) {
        o = *(const bf16x8*)((const bf16_t*)src + i0);
    } else {
        const float* s = (const float*)src + i0;
        float4 a = *(const float4*)s;
        float4 b = *(const float4*)(s + 4);
        o[0] = (bf16_t)a.x; o[1] = (bf16_t)a.y; o[2] = (bf16_t)a.z; o[3] = (bf16_t)a.w;
        o[4] = (bf16_t)b.x; o[5] = (bf16_t)b.y; o[6] = (bf16_t)b.z; o[7] = (bf16_t)b.w;
    }
    *(bf16x8*)(dst + i0) = o;
}

// ---------------------------------------------------------------------------
// Transpose 2048x2048 -> bf16: dst[n][k] = (bf16)src[k][n]. grid (32,32,5).
// ---------------------------------------------------------------------------
__global__ __launch_bounds__(256) void transpose_k(TPtrs p, const int* __restrict__ flag) {
    __shared__ bf16_t tile[64][72];  // +8 pad
    int z = blockIdx.z;
    bf16_t* dst = p.dst[z];
    int bx = blockIdx.x, by = blockIdx.y;
    int tid = threadIdx.x;
    int isbf = *flag;
#pragma unroll
    for (int l = 0; l < 2; ++l) {
        int idx = tid + 256 * l;          // 512 x 8 elems = 64 rows x 64 cols
        int r = idx >> 3, c8 = (idx & 7) * 8;
        bf16x8 o;
        if (isbf) {
            const bf16_t* src = (const bf16_t*)p.src[z];
            o = *(const bf16x8*)&src[(size_t)(by * 64 + r) * 2048 + bx * 64 + c8];
        } else {
            const float* src = (const float*)p.src[z];
            const float* sp = &src[(size_t)(by * 64 + r) * 2048 + bx * 64 + c8];
            float4 a = *(const float4*)sp;
            float4 b = *(const float4*)(sp + 4);
            o[0] = (bf16_t)a.x; o[1] = (bf16_t)a.y; o[2] = (bf16_t)a.z; o[3] = (bf16_t)a.w;
            o[4] = (bf16_t)b.x; o[5] = (bf16_t)b.y; o[6] = (bf16_t)b.z; o[7] = (bf16_t)b.w;
        }
        *(bf16x8*)&tile[r][c8] = o;
    }
    __syncthreads();
#pragma unroll
    for (int l = 0; l < 2; ++l) {
        int idx = tid + 256 * l;
        int r = idx >> 3, c8 = (idx & 7) * 8;
        bf16x8 o;
#pragma unroll
        for (int m = 0; m < 8; ++m) o[m] = tile[c8 + m][r];
        *(bf16x8*)&dst[(size_t)(bx * 64 + r) * 2048 + by * 64 + c8] = o;
    }
}

// ---------------------------------------------------------------------------
// GEMM  C[M,N] = A[M,K] @ Bt[N,K]^T, bf16 out.  m97 staging + XOR swizzle:
// LDS slot (row, c) holds global chunk (row, c ^ (row&7)); fragment chunk k
// is read at chunk index k ^ (l15&7)  -> bank-conflict-free ds_read_b128.
// blockIdx.z selects Bt/C pair (QKVG fused launch).
// ---------------------------------------------------------------------------
__global__ __launch_bounds__(256) void gemm_bt(const bf16_t* __restrict__ A, GPtrs p,
                                               int K) {
    __shared__ bf16_t sA[128 * 64];
    __shared__ bf16_t sB[128 * 64];
    const bf16_t* __restrict__ Bt = p.Bt[blockIdx.z];
    bf16_t* __restrict__ C = p.C[blockIdx.z];
    const int N = 2048;
    int tid = threadIdx.x, lane = tid & 63, wid = tid >> 6;
    int l15 = lane & 15, quad = lane >> 4;
    int wm = wid >> 1, wn = wid & 1;
    int m0 = blockIdx.y * 128, n0 = blockIdx.x * 128;

    // staging: call l, wave w, lane i -> LDS slot (row = l*32 + tid>>3, c = tid&7)
    // fetch global chunk c ^ (row&7)  (row&7 == (tid>>3)&7, l-invariant)
    int srow = tid >> 3;
    int sc8 = (((tid & 7) ^ (srow & 7)) * 8);
    const bf16_t* ga = &A[(size_t)(m0 + srow) * K + sc8];
    const bf16_t* gb = &Bt[(size_t)(n0 + srow) * K + sc8];
    bf16_t* la = &sA[(size_t)(wid * 64) * 8];
    bf16_t* lb = &sB[(size_t)(wid * 64) * 8];
    const size_t rstep = (size_t)32 * K;      // 256 threads / 8 per row

    int x7 = l15 & 7;                         // read-side swizzle key

    floatx4 acc[4][4] = {};
    for (int kk = 0; kk < K; kk += 64) {
#pragma unroll
        for (int l = 0; l < 4; ++l)
            gload_lds16(ga + l * rstep + kk, la + l * 2048);
#pragma unroll
        for (int l = 0; l < 4; ++l)
            gload_lds16(gb + l * rstep + kk, lb + l * 2048);
        __syncthreads();
#pragma unroll
        for (int k2 = 0; k2 < 2; ++k2) {
            int koff = ((k2 * 4 + quad) ^ x7) * 8;   // swizzled chunk offset
            bf16x8 af[4], bfv[4];
#pragma unroll
            for (int i = 0; i < 4; ++i)
                af[i] = *(const bf16x8*)&sA[(wm * 64 + i * 16 + l15) * 64 + koff];
#pragma unroll
            for (int j = 0; j < 4; ++j)
                bfv[j] = *(const bf16x8*)&sB[(wn * 64 + j * 16 + l15) * 64 + koff];
#pragma unroll
            for (int i = 0; i < 4; ++i)
#pragma unroll
                for (int j = 0; j < 4; ++j)
                    acc[i][j] = MFMA16(af[i], bfv[j], acc[i][j]);
        }
        __syncthreads();
    }
#pragma unroll
    for (int i = 0; i < 4; ++i)
#pragma unroll
        for (int j = 0; j < 4; ++j)
#pragma unroll
            for (int r = 0; r < 4; ++r) {
                int row = m0 + wm * 64 + i * 16 + quad * 4 + r;
                int col = n0 + wn * 64 + j * 16 + l15;
                C[(size_t)row * N + col] = (bf16_t)acc[i][j][r];
            }
}

// ---------------------------------------------------------------------------
// Final GEMM: out dtype dynamic (flag=1 -> bf16, else fp32).  Same structure.
// ---------------------------------------------------------------------------
__global__ __launch_bounds__(256) void gemm_bt_dyn(const bf16_t* __restrict__ A,
                                                   const bf16_t* __restrict__ Bt,
                                                   void* __restrict__ C, int K,
                                                   const int* __restrict__ flag) {
    __shared__ bf16_t sA[128 * 64];
    __shared__ bf16_t sB[128 * 64];
    const int N = 2048;
    int tid = threadIdx.x, lane = tid & 63, wid = tid >> 6;
    int l15 = lane & 15, quad = lane >> 4;
    int wm = wid >> 1, wn = wid & 1;
    int m0 = blockIdx.y * 128, n0 = blockIdx.x * 128;
    int isbf = *flag;

    int srow = tid >> 3;
    int sc8 = (((tid & 7) ^ (srow & 7)) * 8);
    const bf16_t* ga = &A[(size_t)(m0 + srow) * K + sc8];
    const bf16_t* gb = &Bt[(size_t)(n0 + srow) * K + sc8];
    bf16_t* la = &sA[(size_t)(wid * 64) * 8];
    bf16_t* lb = &sB[(size_t)(wid * 64) * 8];
    const size_t rstep = (size_t)32 * K;
    int x7 = l15 & 7;

    floatx4 acc[4][4] = {};
    for (int kk = 0; kk < K; kk += 64) {
#pragma unroll
        for (int l = 0; l < 4; ++l)
            gload_lds16(ga + l * rstep + kk, la + l * 2048);
#pragma unroll
        for (int l = 0; l < 4; ++l)
            gload_lds16(gb + l * rstep + kk, lb + l * 2048);
        __syncthreads();
#pragma unroll
        for (int k2 = 0; k2 < 2; ++k2) {
            int koff = ((k2 * 4 + quad) ^ x7) * 8;
            bf16x8 af[4], bfv[4];
#pragma unroll
            for (int i = 0; i < 4; ++i)
                af[i] = *(const bf16x8*)&sA[(wm * 64 + i * 16 + l15) * 64 + koff];
#pragma unroll
            for (int j = 0; j < 4; ++j)
                bfv[j] = *(const bf16x8*)&sB[(wn * 64 + j * 16 + l15) * 64 + koff];
#pragma unroll
            for (int i = 0; i < 4; ++i)
#pragma unroll
                for (int j = 0; j < 4; ++j)
                    acc[i][j] = MFMA16(af[i], bfv[j], acc[i][j]);
        }
        __syncthreads();
    }
#pragma unroll
    for (int i = 0; i < 4; ++i)
#pragma unroll
        for (int j = 0; j < 4; ++j)
#pragma unroll
            for (int r = 0; r < 4; ++r) {
                int row = m0 + wm * 64 + i * 16 + quad * 4 + r;
                int col = n0 + wn * 64 + j * 16 + l15;
                if (isbf) ((bf16_t*)C)[(size_t)row * N + col] = (bf16_t)acc[i][j][r];
                else      ((float*)C)[(size_t)row * N + col] = acc[i][j][r];
            }
}

// ---------------------------------------------------------------------------
// RoPE (rotate-half, base 10000) in place on q and k; q also scaled.
// grid 32768: first half q, second half k.
// ---------------------------------------------------------------------------
__global__ __launch_bounds__(256) void rope_kernel(bf16_t* Q, bf16_t* Kb) {
    int isq = blockIdx.x < 16384;
    bf16_t* X = isq ? Q : Kb;
    float scale = isq ? 0.08838834764831845f : 1.0f;
    size_t gt = (size_t)(blockIdx.x & 16383) * 256 + threadIdx.x;
    int i = gt & 63;
    int h = (gt >> 6) & 15;
    int s = (gt >> 10) & 2047;
    int b = gt >> 21;
    size_t base = ((size_t)((b * 2048 + s) * 16 + h)) << 7;
    float inv = exp2f(-(float)i * (13.287712379549449f / 64.f));  // 10000^(-i/64)
    float ang = (float)s * inv;
    float sn, cs;
    sincosf(ang, &sn, &cs);
    float x1 = (float)X[base + i];
    float x2 = (float)X[base + 64 + i];
    X[base + i]      = (bf16_t)((x1 * cs - x2 * sn) * scale);
    X[base + 64 + i] = (bf16_t)((x2 * cs + x1 * sn) * scale);
}

// ---------------------------------------------------------------------------
// Pass A: Ut[e][d] = sum_t v[t][e] * gamma^(63-t) * k[t][d].  grid 1024.
// ---------------------------------------------------------------------------
__global__ __launch_bounds__(256) void chunk_state_kernel(const bf16_t* __restrict__ Kc,
                                                          const bf16_t* __restrict__ Vc,
                                                          bf16_t* __restrict__ U) {
    __shared__ bf16_t sKT[128][72];
    __shared__ bf16_t sVT[128][72];
    int bx = blockIdx.x;
    int n = bx & 31, h = (bx >> 5) & 15, b = bx >> 9;
    int tid = threadIdx.x, lane = tid & 63, wid = tid >> 6;
    int l15 = lane & 15, quad = lane >> 4;
    int wm = wid >> 1, wn = wid & 1;
    float log2g = log2f(1.f - exp2f(-5.f - (float)h));

#pragma unroll
    for (int l = 0; l < 4; ++l) {
        int idx = tid + 256 * l;          // 1024 = 64 rows x 16 vec8
        int t = idx >> 4, d8 = (idx & 15) * 8;
        size_t gb = (((size_t)((b * 2048 + n * 64 + t) * 16 + h)) << 7) + d8;
        bf16x8 kv = *(const bf16x8*)&Kc[gb];
        bf16x8 vv = *(const bf16x8*)&Vc[gb];
        float kdec = exp2f((float)(63 - t) * log2g);
#pragma unroll
        for (int m = 0; m < 8; ++m) {
            sKT[d8 + m][t] = (bf16_t)((float)kv[m] * kdec);
            sVT[d8 + m][t] = vv[m];
        }
    }
    __syncthreads();

    floatx4 acc[4][4] = {};
#pragma unroll
    for (int k2 = 0; k2 < 2; ++k2) {
        int t0 = k2 * 32 + quad * 8;
        bf16x8 af[4], bfv[4];
#pragma unroll
        for (int i = 0; i < 4; ++i) af[i] = *(const bf16x8*)&sVT[wm * 64 + i * 16 + l15][t0];
#pragma unroll
        for (int j = 0; j < 4; ++j) bfv[j] = *(const bf16x8*)&sKT[wn * 64 + j * 16 + l15][t0];
#pragma unroll
        for (int i = 0; i < 4; ++i)
#pragma unroll
            for (int j = 0; j < 4; ++j) acc[i][j] = MFMA16(af[i], bfv[j], acc[i][j]);
    }
    size_t ub = (size_t)bx * 16384;
#pragma unroll
    for (int i = 0; i < 4; ++i)
#pragma unroll
        for (int j = 0; j < 4; ++j)
#pragma unroll
            for (int r = 0; r < 4; ++r) {
                int e = wm * 64 + i * 16 + quad * 4 + r;
                int d = wn * 64 + j * 16 + l15;
                U[ub + (size_t)e * 128 + d] = (bf16_t)acc[i][j][r];
            }
}

// ---------------------------------------------------------------------------
// Pass B: in-place scan  St[n] = state before chunk n (transposed layout).
// ---------------------------------------------------------------------------
__global__ __launch_bounds__(256) void scan_kernel(bf16_t* __restrict__ US) {
    int bx = blockIdx.x;
    int bh = bx >> 3, slice = bx & 7;
    int h = bh & 15;
    float log2g = log2f(1.f - exp2f(-5.f - (float)h));
    float gC = exp2f(64.f * log2g);
    size_t base = (size_t)bh * 32 * 16384 + (size_t)slice * 2048 + (size_t)threadIdx.x * 8;
    float acc[8] = {};
    for (int n = 0; n < 32; ++n) {
        size_t o = base + (size_t)n * 16384;
        bf16x8 u = *(const bf16x8*)&US[o];
        bf16x8 s;
#pragma unroll
        for (int m = 0; m < 8; ++m) s[m] = (bf16_t)acc[m];
        *(bf16x8*)&US[o] = s;
#pragma unroll
        for (int m = 0; m < 8; ++m) acc[m] = gC * acc[m] + (float)u[m];
    }
}

// ---------------------------------------------------------------------------
// Pass C: chunk output + gated RMSNorm.  grid 1024.
// ---------------------------------------------------------------------------
__global__ __launch_bounds__(256) void chunk_out_kernel(
    const bf16_t* __restrict__ Q, const bf16_t* __restrict__ Kc,
    const bf16_t* __restrict__ Vc, const bf16_t* __restrict__ G,
    const void* __restrict__ gwp, const bf16_t* __restrict__ St,
    bf16_t* __restrict__ OG, const int* __restrict__ flag) {
    __shared__ bf16_t sQ[64][136];
    __shared__ bf16_t sK[64][136];
    __shared__ bf16_t sVT[128][72];
    __shared__ bf16_t sA[64][72];
    __shared__ float sgw[128];
    int bx = blockIdx.x;
    int n = bx & 31, h = (bx >> 5) & 15, b = bx >> 9;
    int tid = threadIdx.x, lane = tid & 63, wid = tid >> 6;
    int l15 = lane & 15, quad = lane >> 4;
    float log2g = log2f(1.f - exp2f(-5.f - (float)h));

    if (tid < 128) {
        sgw[tid] = (*flag) ? (float)((const bf16_t*)gwp)[tid] : ((const float*)gwp)[tid];
    }
#pragma unroll
    for (int l = 0; l < 4; ++l) {
        int idx = tid + 256 * l;
        int t = idx >> 4, d8 = (idx & 15) * 8;
        size_t gb = (((size_t)((b * 2048 + n * 64 + t) * 16 + h)) << 7) + d8;
        *(bf16x8*)&sQ[t][d8] = *(const bf16x8*)&Q[gb];
        *(bf16x8*)&sK[t][d8] = *(const bf16x8*)&Kc[gb];
        bf16x8 vv = *(const bf16x8*)&Vc[gb];
#pragma unroll
        for (int m = 0; m < 8; ++m) sVT[d8 + m][t] = vv[m];
    }
    __syncthreads();

    // ---- phase 1: A = q k^T (64x64), decay mask, stash bf16 in sA
    int t0 = wid * 16;
    floatx4 accA[4] = {};
#pragma unroll
    for (int kk = 0; kk < 4; ++kk) {
        int d0 = kk * 32 + quad * 8;
        bf16x8 aq = *(const bf16x8*)&sQ[t0 + l15][d0];
#pragma unroll
        for (int j = 0; j < 4; ++j) {
            bf16x8 bk = *(const bf16x8*)&sK[j * 16 + l15][d0];
            accA[j] = MFMA16(aq, bk, accA[j]);
        }
    }
#pragma unroll
    for (int j = 0; j < 4; ++j)
#pragma unroll
        for (int r = 0; r < 4; ++r) {
            int t = t0 + quad * 4 + r;
            int s = j * 16 + l15;
            int rel = t - s;
            float v = (rel >= 0) ? accA[j][r] * exp2f((float)rel * log2g) : 0.f;
            sA[t][s] = (bf16_t)v;
        }
    __syncthreads();

    // ---- phase 2: o = A v + (q*cross) S
    floatx4 acc[8] = {};
#pragma unroll
    for (int kk = 0; kk < 2; ++kk) {          // K = 64 (s)
        int s0 = kk * 32 + quad * 8;
        bf16x8 aa = *(const bf16x8*)&sA[t0 + l15][s0];
#pragma unroll
        for (int j = 0; j < 8; ++j) {
            bf16x8 bv = *(const bf16x8*)&sVT[j * 16 + l15][s0];
            acc[j] = MFMA16(aa, bv, acc[j]);
        }
    }
    size_t sb = (size_t)bx * 16384;
    float crossf = exp2f((float)(t0 + l15 + 1) * log2g);
#pragma unroll
    for (int kk = 0; kk < 4; ++kk) {          // K = 128 (d)
        int d0 = kk * 32 + quad * 8;
        bf16x8 aq = *(const bf16x8*)&sQ[t0 + l15][d0];
        bf16x8 aqs;
#pragma unroll
        for (int m = 0; m < 8; ++m) aqs[m] = (bf16_t)((float)aq[m] * crossf);
#pragma unroll
        for (int j = 0; j < 8; ++j) {
            bf16x8 bs = *(const bf16x8*)&St[sb + (size_t)(j * 16 + l15) * 128 + d0];
            acc[j] = MFMA16(aqs, bs, acc[j]);
        }
    }

    // ---- epilogue: gated RMSNorm per row t
#pragma unroll
    for (int r = 0; r < 4; ++r) {
        float ss = 0.f;
#pragma unroll
        for (int j = 0; j < 8; ++j) ss += acc[j][r] * acc[j][r];
        ss += __shfl_xor(ss, 1);
        ss += __shfl_xor(ss, 2);
        ss += __shfl_xor(ss, 4);
        ss += __shfl_xor(ss, 8);
        float rms = rsqrtf(ss * (1.f / 128.f) + 1e-5f);
        int t = t0 + quad * 4 + r;
        size_t gb = ((size_t)((b * 2048 + n * 64 + t) * 16 + h)) << 7;
#pragma unroll
        for (int j = 0; j < 8; ++j) {
            int e = j * 16 + l15;
            float g_ = (float)G[gb + e];
            float sw = g_ / (1.f + expf(-g_));
            OG[gb + e] = (bf16_t)(acc[j][r] * rms * sgw[e] * sw);
        }
    }
}

// ---------------------------------------------------------------------------
extern "C" void kernel_launch(void* const* d_in, const int* in_sizes, int n_in,
                              void* d_out, int out_size, void* d_ws, size_t ws_size,
                              hipStream_t stream) {
    char* ws = (char*)d_ws;
    const size_t WBYTES = 2048ull * 2048 * 2;   // 8 MiB per bf16 weight
    const size_t ABYTES = 4096ull * 2048 * 2;   // 16 MiB per bf16 activation
    int* flag = (int*)ws;
    char* base = ws + 256;
    bf16_t* xb = (bf16_t*)base;
    bf16_t* WT[5];
    for (int i = 0; i < 5; ++i) WT[i] = (bf16_t*)(base + ABYTES + i * WBYTES);
    char* act = base + ABYTES + 5 * WBYTES;
    bf16_t* qb = (bf16_t*)(act + 0 * ABYTES);
    bf16_t* kb = (bf16_t*)(act + 1 * ABYTES);
    bf16_t* vb = (bf16_t*)(act + 2 * ABYTES);
    bf16_t* gb = (bf16_t*)(act + 3 * ABYTES);
    bf16_t* og = (bf16_t*)(act + 4 * ABYTES);
    bf16_t* US = (bf16_t*)(act + 5 * ABYTES);  // 32 MiB

    // 0. detect dtype (flag=1 -> bf16 inputs)
    detect_dtype_kernel<<<1, 256, 0, stream>>>((const unsigned int*)d_in[1], flag);

    // 1. canonicalize x; transpose+canonicalize all 5 weights
    convert_x_kernel<<<4096, 256, 0, stream>>>(d_in[0], xb, flag);
    TPtrs tp;
    tp.src[0] = d_in[1]; tp.src[1] = d_in[2]; tp.src[2] = d_in[3];
    tp.src[3] = d_in[4]; tp.src[4] = d_in[6];
    for (int i = 0; i < 5; ++i) tp.dst[i] = WT[i];
    transpose_k<<<dim3(32, 32, 5), 256, 0, stream>>>(tp, flag);

    // 2. fused QKVG projections
    GPtrs gp;
    gp.Bt[0] = WT[0]; gp.Bt[1] = WT[1]; gp.Bt[2] = WT[2]; gp.Bt[3] = WT[3];
    gp.C[0] = qb; gp.C[1] = kb; gp.C[2] = vb; gp.C[3] = gb;
    gemm_bt<<<dim3(16, 32, 4), 256, 0, stream>>>(xb, gp, 2048);

    // 3. RoPE (q scaled by DK^-0.5) — q and k in one dispatch
    rope_kernel<<<32768, 256, 0, stream>>>(qb, kb);

    // 4. retention
    chunk_state_kernel<<<1024, 256, 0, stream>>>(kb, vb, US);
    scan_kernel<<<256, 256, 0, stream>>>(US);
    chunk_out_kernel<<<1024, 256, 0, stream>>>(qb, kb, vb, gb, d_in[5], US, og, flag);

    // 5. output projection (dtype-dynamic store)
    gemm_bt_dyn<<<dim3(16, 32, 1), 256, 0, stream>>>(og, WT[4], d_out, 2048, flag);
}

// Round 5
// 426.877 us; speedup vs baseline: 1.1475x; 1.0453x over previous
//
#include <hip/hip_runtime.h>

typedef __bf16 bf16_t;
typedef __bf16 bf16x8 __attribute__((ext_vector_type(8)));
typedef float floatx4 __attribute__((ext_vector_type(4)));

#define MFMA16(a, b, c) __builtin_amdgcn_mfma_f32_16x16x32_bf16(a, b, c, 0, 0, 0)

#define AS1 __attribute__((address_space(1)))
#define AS3 __attribute__((address_space(3)))

// async 16B global -> LDS (lane i lands at ldsbase + i*16; ldsbase wave-uniform)
__device__ __forceinline__ void gload_lds16(const bf16_t* g, bf16_t* l) {
    __builtin_amdgcn_global_load_lds((const AS1 unsigned int*)g,
                                     (AS3 unsigned int*)l, 16, 0, 0);
}

struct TPtrs { const void* src[5]; bf16_t* dst[5]; };
struct GPtrs { const bf16_t* Bt[4]; bf16_t* C[4]; };

// ---------------------------------------------------------------------------
// Detect input dtype on-device (flag=1 -> bf16 inputs; measured: fp32 world).
// ---------------------------------------------------------------------------
__global__ __launch_bounds__(256) void detect_dtype_kernel(const unsigned int* W,
                                                           int* flag) {
    int tid = threadIdx.x;
    int cnt = 0;
    for (int i = tid; i < 4096; i += 256) {
        unsigned int fb = (W[i] & 0xFFFFu) << 16;
        float v = __uint_as_float(fb);
        float a = fabsf(v);
        if (a > 1e-5f && a < 4.f) cnt++;
    }
    __shared__ int s[256];
    s[tid] = cnt;
    __syncthreads();
    for (int st = 128; st > 0; st >>= 1) {
        if (tid < st) s[tid] += s[tid + st];
        __syncthreads();
    }
    if (tid == 0) *flag = (s[0] > 2048) ? 1 : 0;
}

// ---------------------------------------------------------------------------
// Canonicalize x -> bf16. 8,388,608 elems, 8/thread, grid 4096.
// ---------------------------------------------------------------------------
__global__ __launch_bounds__(256) void convert_x_kernel(const void* __restrict__ src,
                                                        bf16_t* __restrict__ dst,
                                                        const int* __restrict__ flag) {
    size_t i0 = ((size_t)blockIdx.x * 256 + threadIdx.x) * 8;
    bf16x8 o;
    if (*flag) {
        o = *(const bf16x8*)((const bf16_t*)src + i0);
    } else {
        const float* s = (const float*)src + i0;
        float4 a = *(const float4*)s;
        float4 b = *(const float4*)(s + 4);
        o[0] = (bf16_t)a.x; o[1] = (bf16_t)a.y; o[2] = (bf16_t)a.z; o[3] = (bf16_t)a.w;
        o[4] = (bf16_t)b.x; o[5] = (bf16_t)b.y; o[6] = (bf16_t)b.z; o[7] = (bf16_t)b.w;
    }
    *(bf16x8*)(dst + i0) = o;
}

// ---------------------------------------------------------------------------
// Transpose 2048x2048 -> bf16: dst[n][k] = (bf16)src[k][n]. grid (32,32,5).
// ---------------------------------------------------------------------------
__global__ __launch_bounds__(256) void transpose_k(TPtrs p, const int* __restrict__ flag) {
    __shared__ bf16_t tile[64][72];  // +8 pad
    int z = blockIdx.z;
    bf16_t* dst = p.dst[z];
    int bx = blockIdx.x, by = blockIdx.y;
    int tid = threadIdx.x;
    int isbf = *flag;
#pragma unroll
    for (int l = 0; l < 2; ++l) {
        int idx = tid + 256 * l;          // 512 x 8 elems = 64 rows x 64 cols
        int r = idx >> 3, c8 = (idx & 7) * 8;
        bf16x8 o;
        if (isbf) {
            const bf16_t* src = (const bf16_t*)p.src[z];
            o = *(const bf16x8*)&src[(size_t)(by * 64 + r) * 2048 + bx * 64 + c8];
        } else {
            const float* src = (const float*)p.src[z];
            const float* sp = &src[(size_t)(by * 64 + r) * 2048 + bx * 64 + c8];
            float4 a = *(const float4*)sp;
            float4 b = *(const float4*)(sp + 4);
            o[0] = (bf16_t)a.x; o[1] = (bf16_t)a.y; o[2] = (bf16_t)a.z; o[3] = (bf16_t)a.w;
            o[4] = (bf16_t)b.x; o[5] = (bf16_t)b.y; o[6] = (bf16_t)b.z; o[7] = (bf16_t)b.w;
        }
        *(bf16x8*)&tile[r][c8] = o;
    }
    __syncthreads();
#pragma unroll
    for (int l = 0; l < 2; ++l) {
        int idx = tid + 256 * l;
        int r = idx >> 3, c8 = (idx & 7) * 8;
        bf16x8 o;
#pragma unroll
        for (int m = 0; m < 8; ++m) o[m] = tile[c8 + m][r];
        *(bf16x8*)&dst[(size_t)(bx * 64 + r) * 2048 + by * 64 + c8] = o;
    }
}

// ---------------------------------------------------------------------------
// QKVG GEMM with fused RoPE.  C[M,N] = A[M,K] @ Bt[N,K]^T, bf16 out.
// m97 staging + XOR swizzle (conflict-free).  Each block spans ONE head
// (BN=128=head dim).  B-fragment j covers col (j&1)*64 + wn*32 + (j>>1)*16
// + l15, so RoPE pairs (c, c+64) are acc[i][2jj] / acc[i][2jj+1] in the
// SAME lane -> rotation is a register-level epilogue (z=0: q*scale, z=1: k).
// ---------------------------------------------------------------------------
__global__ __launch_bounds__(256) void gemm_bt(const bf16_t* __restrict__ A, GPtrs p,
                                               int K) {
    __shared__ bf16_t sA[128 * 64];
    __shared__ bf16_t sB[128 * 64];
    int z = blockIdx.z;
    const bf16_t* __restrict__ Bt = p.Bt[z];
    bf16_t* __restrict__ C = p.C[z];
    const int N = 2048;
    int tid = threadIdx.x, lane = tid & 63, wid = tid >> 6;
    int l15 = lane & 15, quad = lane >> 4;
    int wm = wid >> 1, wn = wid & 1;
    int m0 = blockIdx.y * 128, n0 = blockIdx.x * 128;

    int srow = tid >> 3;
    int sc8 = (((tid & 7) ^ (srow & 7)) * 8);
    const bf16_t* ga = &A[(size_t)(m0 + srow) * K + sc8];
    const bf16_t* gb = &Bt[(size_t)(n0 + srow) * K + sc8];
    bf16_t* la = &sA[(size_t)(wid * 64) * 8];
    bf16_t* lb = &sB[(size_t)(wid * 64) * 8];
    const size_t rstep = (size_t)32 * K;
    int x7 = l15 & 7;

    // B-fragment rows: pair cols (c, c+64) into adjacent j
    int jrow[4];
#pragma unroll
    for (int j = 0; j < 4; ++j)
        jrow[j] = (j & 1) * 64 + wn * 32 + (j >> 1) * 16 + l15;

    floatx4 acc[4][4] = {};
    for (int kk = 0; kk < K; kk += 64) {
#pragma unroll
        for (int l = 0; l < 4; ++l)
            gload_lds16(ga + l * rstep + kk, la + l * 2048);
#pragma unroll
        for (int l = 0; l < 4; ++l)
            gload_lds16(gb + l * rstep + kk, lb + l * 2048);
        __syncthreads();
#pragma unroll
        for (int k2 = 0; k2 < 2; ++k2) {
            int koff = ((k2 * 4 + quad) ^ x7) * 8;
            bf16x8 af[4], bfv[4];
#pragma unroll
            for (int i = 0; i < 4; ++i)
                af[i] = *(const bf16x8*)&sA[(wm * 64 + i * 16 + l15) * 64 + koff];
#pragma unroll
            for (int j = 0; j < 4; ++j)
                bfv[j] = *(const bf16x8*)&sB[jrow[j] * 64 + koff];
#pragma unroll
            for (int i = 0; i < 4; ++i)
#pragma unroll
                for (int j = 0; j < 4; ++j)
                    acc[i][j] = MFMA16(af[i], bfv[j], acc[i][j]);
        }
        __syncthreads();
    }

    if (z < 2) {
        // ---- fused RoPE epilogue (q: scaled, k: unscaled)
        float scale = (z == 0) ? 0.08838834764831845f : 1.0f;
#pragma unroll
        for (int jj = 0; jj < 2; ++jj) {
            int c = wn * 32 + jj * 16 + l15;                     // [0,64)
            float inv = exp2f(-(float)c * (13.287712379549449f / 64.f));
#pragma unroll
            for (int i = 0; i < 4; ++i)
#pragma unroll
                for (int r = 0; r < 4; ++r) {
                    int row = m0 + wm * 64 + i * 16 + quad * 4 + r;
                    float ang = (float)(row & 2047) * inv;
                    float sn, cs;
                    __sincosf(ang, &sn, &cs);
                    float x1 = acc[i][2 * jj][r], x2 = acc[i][2 * jj + 1][r];
                    size_t ro = (size_t)row * N + n0 + c;
                    C[ro]      = (bf16_t)((x1 * cs - x2 * sn) * scale);
                    C[ro + 64] = (bf16_t)((x2 * cs + x1 * sn) * scale);
                }
        }
    } else {
#pragma unroll
        for (int i = 0; i < 4; ++i)
#pragma unroll
            for (int j = 0; j < 4; ++j)
#pragma unroll
                for (int r = 0; r < 4; ++r) {
                    int row = m0 + wm * 64 + i * 16 + quad * 4 + r;
                    int col = n0 + jrow[j];
                    C[(size_t)row * N + col] = (bf16_t)acc[i][j][r];
                }
    }
}

// ---------------------------------------------------------------------------
// Final GEMM: out dtype dynamic (flag=1 -> bf16, else fp32).
// ---------------------------------------------------------------------------
__global__ __launch_bounds__(256) void gemm_bt_dyn(const bf16_t* __restrict__ A,
                                                   const bf16_t* __restrict__ Bt,
                                                   void* __restrict__ C, int K,
                                                   const int* __restrict__ flag) {
    __shared__ bf16_t sA[128 * 64];
    __shared__ bf16_t sB[128 * 64];
    const int N = 2048;
    int tid = threadIdx.x, lane = tid & 63, wid = tid >> 6;
    int l15 = lane & 15, quad = lane >> 4;
    int wm = wid >> 1, wn = wid & 1;
    int m0 = blockIdx.y * 128, n0 = blockIdx.x * 128;
    int isbf = *flag;

    int srow = tid >> 3;
    int sc8 = (((tid & 7) ^ (srow & 7)) * 8);
    const bf16_t* ga = &A[(size_t)(m0 + srow) * K + sc8];
    const bf16_t* gb = &Bt[(size_t)(n0 + srow) * K + sc8];
    bf16_t* la = &sA[(size_t)(wid * 64) * 8];
    bf16_t* lb = &sB[(size_t)(wid * 64) * 8];
    const size_t rstep = (size_t)32 * K;
    int x7 = l15 & 7;

    floatx4 acc[4][4] = {};
    for (int kk = 0; kk < K; kk += 64) {
#pragma unroll
        for (int l = 0; l < 4; ++l)
            gload_lds16(ga + l * rstep + kk, la + l * 2048);
#pragma unroll
        for (int l = 0; l < 4; ++l)
            gload_lds16(gb + l * rstep + kk, lb + l * 2048);
        __syncthreads();
#pragma unroll
        for (int k2 = 0; k2 < 2; ++k2) {
            int koff = ((k2 * 4 + quad) ^ x7) * 8;
            bf16x8 af[4], bfv[4];
#pragma unroll
            for (int i = 0; i < 4; ++i)
                af[i] = *(const bf16x8*)&sA[(wm * 64 + i * 16 + l15) * 64 + koff];
#pragma unroll
            for (int j = 0; j < 4; ++j)
                bfv[j] = *(const bf16x8*)&sB[(wn * 64 + j * 16 + l15) * 64 + koff];
#pragma unroll
            for (int i = 0; i < 4; ++i)
#pragma unroll
                for (int j = 0; j < 4; ++j)
                    acc[i][j] = MFMA16(af[i], bfv[j], acc[i][j]);
        }
        __syncthreads();
    }
#pragma unroll
    for (int i = 0; i < 4; ++i)
#pragma unroll
        for (int j = 0; j < 4; ++j)
#pragma unroll
            for (int r = 0; r < 4; ++r) {
                int row = m0 + wm * 64 + i * 16 + quad * 4 + r;
                int col = n0 + wn * 64 + j * 16 + l15;
                if (isbf) ((bf16_t*)C)[(size_t)row * N + col] = (bf16_t)acc[i][j][r];
                else      ((float*)C)[(size_t)row * N + col] = acc[i][j][r];
            }
}

// ---------------------------------------------------------------------------
// Pass A: Ut[e][d] = sum_t v[t][e] * gamma^(63-t) * k[t][d].  grid 1024.
// ---------------------------------------------------------------------------
__global__ __launch_bounds__(256) void chunk_state_kernel(const bf16_t* __restrict__ Kc,
                                                          const bf16_t* __restrict__ Vc,
                                                          bf16_t* __restrict__ U) {
    __shared__ bf16_t sKT[128][72];
    __shared__ bf16_t sVT[128][72];
    int bx = blockIdx.x;
    int n = bx & 31, h = (bx >> 5) & 15, b = bx >> 9;
    int tid = threadIdx.x, lane = tid & 63, wid = tid >> 6;
    int l15 = lane & 15, quad = lane >> 4;
    int wm = wid >> 1, wn = wid & 1;
    float log2g = log2f(1.f - exp2f(-5.f - (float)h));

#pragma unroll
    for (int l = 0; l < 4; ++l) {
        int idx = tid + 256 * l;          // 1024 = 64 rows x 16 vec8
        int t = idx >> 4, d8 = (idx & 15) * 8;
        size_t gb = (((size_t)((b * 2048 + n * 64 + t) * 16 + h)) << 7) + d8;
        bf16x8 kv = *(const bf16x8*)&Kc[gb];
        bf16x8 vv = *(const bf16x8*)&Vc[gb];
        float kdec = exp2f((float)(63 - t) * log2g);
#pragma unroll
        for (int m = 0; m < 8; ++m) {
            sKT[d8 + m][t] = (bf16_t)((float)kv[m] * kdec);
            sVT[d8 + m][t] = vv[m];
        }
    }
    __syncthreads();

    floatx4 acc[4][4] = {};
#pragma unroll
    for (int k2 = 0; k2 < 2; ++k2) {
        int t0 = k2 * 32 + quad * 8;
        bf16x8 af[4], bfv[4];
#pragma unroll
        for (int i = 0; i < 4; ++i) af[i] = *(const bf16x8*)&sVT[wm * 64 + i * 16 + l15][t0];
#pragma unroll
        for (int j = 0; j < 4; ++j) bfv[j] = *(const bf16x8*)&sKT[wn * 64 + j * 16 + l15][t0];
#pragma unroll
        for (int i = 0; i < 4; ++i)
#pragma unroll
            for (int j = 0; j < 4; ++j) acc[i][j] = MFMA16(af[i], bfv[j], acc[i][j]);
    }
    size_t ub = (size_t)bx * 16384;
#pragma unroll
    for (int i = 0; i < 4; ++i)
#pragma unroll
        for (int j = 0; j < 4; ++j)
#pragma unroll
            for (int r = 0; r < 4; ++r) {
                int e = wm * 64 + i * 16 + quad * 4 + r;
                int d = wn * 64 + j * 16 + l15;
                U[ub + (size_t)e * 128 + d] = (bf16_t)acc[i][j][r];
            }
}

// ---------------------------------------------------------------------------
// Pass B: in-place scan  St[n] = state before chunk n (transposed layout).
// ---------------------------------------------------------------------------
__global__ __launch_bounds__(256) void scan_kernel(bf16_t* __restrict__ US) {
    int bx = blockIdx.x;
    int bh = bx >> 3, slice = bx & 7;
    int h = bh & 15;
    float log2g = log2f(1.f - exp2f(-5.f - (float)h));
    float gC = exp2f(64.f * log2g);
    size_t base = (size_t)bh * 32 * 16384 + (size_t)slice * 2048 + (size_t)threadIdx.x * 8;
    float acc[8] = {};
    for (int n = 0; n < 32; ++n) {
        size_t o = base + (size_t)n * 16384;
        bf16x8 u = *(const bf16x8*)&US[o];
        bf16x8 s;
#pragma unroll
        for (int m = 0; m < 8; ++m) s[m] = (bf16_t)acc[m];
        *(bf16x8*)&US[o] = s;
#pragma unroll
        for (int m = 0; m < 8; ++m) acc[m] = gC * acc[m] + (float)u[m];
    }
}

// ---------------------------------------------------------------------------
// Pass C: chunk output + gated RMSNorm.  grid 1024.
// ---------------------------------------------------------------------------
__global__ __launch_bounds__(256) void chunk_out_kernel(
    const bf16_t* __restrict__ Q, const bf16_t* __restrict__ Kc,
    const bf16_t* __restrict__ Vc, const bf16_t* __restrict__ G,
    const void* __restrict__ gwp, const bf16_t* __restrict__ St,
    bf16_t* __restrict__ OG, const int* __restrict__ flag) {
    __shared__ bf16_t sQ[64][136];
    __shared__ bf16_t sK[64][136];
    __shared__ bf16_t sVT[128][72];
    __shared__ bf16_t sA[64][72];
    __shared__ float sgw[128];
    int bx = blockIdx.x;
    int n = bx & 31, h = (bx >> 5) & 15, b = bx >> 9;
    int tid = threadIdx.x, lane = tid & 63, wid = tid >> 6;
    int l15 = lane & 15, quad = lane >> 4;
    float log2g = log2f(1.f - exp2f(-5.f - (float)h));

    if (tid < 128) {
        sgw[tid] = (*flag) ? (float)((const bf16_t*)gwp)[tid] : ((const float*)gwp)[tid];
    }
#pragma unroll
    for (int l = 0; l < 4; ++l) {
        int idx = tid + 256 * l;
        int t = idx >> 4, d8 = (idx & 15) * 8;
        size_t gb = (((size_t)((b * 2048 + n * 64 + t) * 16 + h)) << 7) + d8;
        *(bf16x8*)&sQ[t][d8] = *(const bf16x8*)&Q[gb];
        *(bf16x8*)&sK[t][d8] = *(const bf16x8*)&Kc[gb];
        bf16x8 vv = *(const bf16x8*)&Vc[gb];
#pragma unroll
        for (int m = 0; m < 8; ++m) sVT[d8 + m][t] = vv[m];
    }
    __syncthreads();

    // ---- phase 1: A = q k^T (64x64), decay mask, stash bf16 in sA
    int t0 = wid * 16;
    floatx4 accA[4] = {};
#pragma unroll
    for (int kk = 0; kk < 4; ++kk) {
        int d0 = kk * 32 + quad * 8;
        bf16x8 aq = *(const bf16x8*)&sQ[t0 + l15][d0];
#pragma unroll
        for (int j = 0; j < 4; ++j) {
            bf16x8 bk = *(const bf16x8*)&sK[j * 16 + l15][d0];
            accA[j] = MFMA16(aq, bk, accA[j]);
        }
    }
#pragma unroll
    for (int j = 0; j < 4; ++j)
#pragma unroll
        for (int r = 0; r < 4; ++r) {
            int t = t0 + quad * 4 + r;
            int s = j * 16 + l15;
            int rel = t - s;
            float v = (rel >= 0) ? accA[j][r] * exp2f((float)rel * log2g) : 0.f;
            sA[t][s] = (bf16_t)v;
        }
    __syncthreads();

    // ---- phase 2: o = A v + (q*cross) S
    floatx4 acc[8] = {};
#pragma unroll
    for (int kk = 0; kk < 2; ++kk) {          // K = 64 (s)
        int s0 = kk * 32 + quad * 8;
        bf16x8 aa = *(const bf16x8*)&sA[t0 + l15][s0];
#pragma unroll
        for (int j = 0; j < 8; ++j) {
            bf16x8 bv = *(const bf16x8*)&sVT[j * 16 + l15][s0];
            acc[j] = MFMA16(aa, bv, acc[j]);
        }
    }
    size_t sb = (size_t)bx * 16384;
    float crossf = exp2f((float)(t0 + l15 + 1) * log2g);
#pragma unroll
    for (int kk = 0; kk < 4; ++kk) {          // K = 128 (d)
        int d0 = kk * 32 + quad * 8;
        bf16x8 aq = *(const bf16x8*)&sQ[t0 + l15][d0];
        bf16x8 aqs;
#pragma unroll
        for (int m = 0; m < 8; ++m) aqs[m] = (bf16_t)((float)aq[m] * crossf);
#pragma unroll
        for (int j = 0; j < 8; ++j) {
            bf16x8 bs = *(const bf16x8*)&St[sb + (size_t)(j * 16 + l15) * 128 + d0];
            acc[j] = MFMA16(aqs, bs, acc[j]);
        }
    }

    // ---- epilogue: gated RMSNorm per row t
#pragma unroll
    for (int r = 0; r < 4; ++r) {
        float ss = 0.f;
#pragma unroll
        for (int j = 0; j < 8; ++j) ss += acc[j][r] * acc[j][r];
        ss += __shfl_xor(ss, 1);
        ss += __shfl_xor(ss, 2);
        ss += __shfl_xor(ss, 4);
        ss += __shfl_xor(ss, 8);
        float rms = rsqrtf(ss * (1.f / 128.f) + 1e-5f);
        int t = t0 + quad * 4 + r;
        size_t gb = ((size_t)((b * 2048 + n * 64 + t) * 16 + h)) << 7;
#pragma unroll
        for (int j = 0; j < 8; ++j) {
            int e = j * 16 + l15;
            float g_ = (float)G[gb + e];
            float sw = g_ / (1.f + __expf(-g_));
            OG[gb + e] = (bf16_t)(acc[j][r] * rms * sgw[e] * sw);
        }
    }
}

// ---------------------------------------------------------------------------
extern "C" void kernel_launch(void* const* d_in, const int* in_sizes, int n_in,
                              void* d_out, int out_size, void* d_ws, size_t ws_size,
                              hipStream_t stream) {
    char* ws = (char*)d_ws;
    const size_t WBYTES = 2048ull * 2048 * 2;   // 8 MiB per bf16 weight
    const size_t ABYTES = 4096ull * 2048 * 2;   // 16 MiB per bf16 activation
    int* flag = (int*)ws;
    char* base = ws + 256;
    bf16_t* xb = (bf16_t*)base;
    bf16_t* WT[5];
    for (int i = 0; i < 5; ++i) WT[i] = (bf16_t*)(base + ABYTES + i * WBYTES);
    char* act = base + ABYTES + 5 * WBYTES;
    bf16_t* qb = (bf16_t*)(act + 0 * ABYTES);
    bf16_t* kb = (bf16_t*)(act + 1 * ABYTES);
    bf16_t* vb = (bf16_t*)(act + 2 * ABYTES);
    bf16_t* gb = (bf16_t*)(act + 3 * ABYTES);
    bf16_t* og = (bf16_t*)(act + 4 * ABYTES);
    bf16_t* US = (bf16_t*)(act + 5 * ABYTES);  // 32 MiB

    // 0. detect dtype (flag=1 -> bf16 inputs)
    detect_dtype_kernel<<<1, 256, 0, stream>>>((const unsigned int*)d_in[1], flag);

    // 1. canonicalize x; transpose+canonicalize all 5 weights
    convert_x_kernel<<<4096, 256, 0, stream>>>(d_in[0], xb, flag);
    TPtrs tp;
    tp.src[0] = d_in[1]; tp.src[1] = d_in[2]; tp.src[2] = d_in[3];
    tp.src[3] = d_in[4]; tp.src[4] = d_in[6];
    for (int i = 0; i < 5; ++i) tp.dst[i] = WT[i];
    transpose_k<<<dim3(32, 32, 5), 256, 0, stream>>>(tp, flag);

    // 2. fused QKVG projections with fused RoPE (z=0: q scaled, z=1: k)
    GPtrs gp;
    gp.Bt[0] = WT[0]; gp.Bt[1] = WT[1]; gp.Bt[2] = WT[2]; gp.Bt[3] = WT[3];
    gp.C[0] = qb; gp.C[1] = kb; gp.C[2] = vb; gp.C[3] = gb;
    gemm_bt<<<dim3(16, 32, 4), 256, 0, stream>>>(xb, gp, 2048);

    // 3. retention
    chunk_state_kernel<<<1024, 256, 0, stream>>>(kb, vb, US);
    scan_kernel<<<256, 256, 0, stream>>>(US);
    chunk_out_kernel<<<1024, 256, 0, stream>>>(qb, kb, vb, gb, d_in[5], US, og, flag);

    // 4. output projection (dtype-dynamic store)
    gemm_bt_dyn<<<dim3(16, 32, 1), 256, 0, stream>>>(og, WT[4], d_out, 2048, flag);
}

// Round 6
// 421.593 us; speedup vs baseline: 1.1618x; 1.0125x over previous
//
#include <hip/hip_runtime.h>

typedef __bf16 bf16_t;
typedef __bf16 bf16x8 __attribute__((ext_vector_type(8)));
typedef float floatx4 __attribute__((ext_vector_type(4)));

#define MFMA16(a, b, c) __builtin_amdgcn_mfma_f32_16x16x32_bf16(a, b, c, 0, 0, 0)

#define AS1 __attribute__((address_space(1)))
#define AS3 __attribute__((address_space(3)))

// async 16B global -> LDS (lane i lands at ldsbase + i*16; ldsbase wave-uniform)
__device__ __forceinline__ void gload_lds16(const bf16_t* g, bf16_t* l) {
    __builtin_amdgcn_global_load_lds((const AS1 unsigned int*)g,
                                     (AS3 unsigned int*)l, 16, 0, 0);
}

struct TPtrs { const void* src[5]; bf16_t* dst[5]; };
struct GPtrs { const bf16_t* Bt[4]; bf16_t* C[4]; };

// ---------------------------------------------------------------------------
// Detect input dtype on-device (flag=1 -> bf16 inputs; measured: fp32 world).
// ---------------------------------------------------------------------------
__global__ __launch_bounds__(256) void detect_dtype_kernel(const unsigned int* W,
                                                           int* flag) {
    int tid = threadIdx.x;
    int cnt = 0;
    for (int i = tid; i < 4096; i += 256) {
        unsigned int fb = (W[i] & 0xFFFFu) << 16;
        float v = __uint_as_float(fb);
        float a = fabsf(v);
        if (a > 1e-5f && a < 4.f) cnt++;
    }
    __shared__ int s[256];
    s[tid] = cnt;
    __syncthreads();
    for (int st = 128; st > 0; st >>= 1) {
        if (tid < st) s[tid] += s[tid + st];
        __syncthreads();
    }
    if (tid == 0) *flag = (s[0] > 2048) ? 1 : 0;
}

// ---------------------------------------------------------------------------
// Canonicalize x -> bf16. 8,388,608 elems, 8/thread, grid 4096.
// ---------------------------------------------------------------------------
__global__ __launch_bounds__(256) void convert_x_kernel(const void* __restrict__ src,
                                                        bf16_t* __restrict__ dst,
                                                        const int* __restrict__ flag) {
    size_t i0 = ((size_t)blockIdx.x * 256 + threadIdx.x) * 8;
    bf16x8 o;
    if (*flag) {
        o = *(const bf16x8*)((const bf16_t*)src + i0);
    } else {
        const float* s = (const float*)src + i0;
        float4 a = *(const float4*)s;
        float4 b = *(const float4*)(s + 4);
        o[0] = (bf16_t)a.x; o[1] = (bf16_t)a.y; o[2] = (bf16_t)a.z; o[3] = (bf16_t)a.w;
        o[4] = (bf16_t)b.x; o[5] = (bf16_t)b.y; o[6] = (bf16_t)b.z; o[7] = (bf16_t)b.w;
    }
    *(bf16x8*)(dst + i0) = o;
}

// ---------------------------------------------------------------------------
// Transpose 2048x2048 -> bf16: dst[n][k] = (bf16)src[k][n]. grid (32,32,5).
// ---------------------------------------------------------------------------
__global__ __launch_bounds__(256) void transpose_k(TPtrs p, const int* __restrict__ flag) {
    __shared__ bf16_t tile[64][72];  // +8 pad
    int z = blockIdx.z;
    bf16_t* dst = p.dst[z];
    int bx = blockIdx.x, by = blockIdx.y;
    int tid = threadIdx.x;
    int isbf = *flag;
#pragma unroll
    for (int l = 0; l < 2; ++l) {
        int idx = tid + 256 * l;          // 512 x 8 elems = 64 rows x 64 cols
        int r = idx >> 3, c8 = (idx & 7) * 8;
        bf16x8 o;
        if (isbf) {
            const bf16_t* src = (const bf16_t*)p.src[z];
            o = *(const bf16x8*)&src[(size_t)(by * 64 + r) * 2048 + bx * 64 + c8];
        } else {
            const float* src = (const float*)p.src[z];
            const float* sp = &src[(size_t)(by * 64 + r) * 2048 + bx * 64 + c8];
            float4 a = *(const float4*)sp;
            float4 b = *(const float4*)(sp + 4);
            o[0] = (bf16_t)a.x; o[1] = (bf16_t)a.y; o[2] = (bf16_t)a.z; o[3] = (bf16_t)a.w;
            o[4] = (bf16_t)b.x; o[5] = (bf16_t)b.y; o[6] = (bf16_t)b.z; o[7] = (bf16_t)b.w;
        }
        *(bf16x8*)&tile[r][c8] = o;
    }
    __syncthreads();
#pragma unroll
    for (int l = 0; l < 2; ++l) {
        int idx = tid + 256 * l;
        int r = idx >> 3, c8 = (idx & 7) * 8;
        bf16x8 o;
#pragma unroll
        for (int m = 0; m < 8; ++m) o[m] = tile[c8 + m][r];
        *(bf16x8*)&dst[(size_t)(bx * 64 + r) * 2048 + by * 64 + c8] = o;
    }
}

// ---------------------------------------------------------------------------
// QKVG GEMM with fused RoPE.  C[M,N] = A[M,K] @ Bt[N,K]^T, bf16 out.
// m97 staging + XOR swizzle (conflict-free).  Each block spans ONE head.
// ---------------------------------------------------------------------------
__global__ __launch_bounds__(256) void gemm_bt(const bf16_t* __restrict__ A, GPtrs p,
                                               int K) {
    __shared__ bf16_t sA[128 * 64];
    __shared__ bf16_t sB[128 * 64];
    int z = blockIdx.z;
    const bf16_t* __restrict__ Bt = p.Bt[z];
    bf16_t* __restrict__ C = p.C[z];
    const int N = 2048;
    int tid = threadIdx.x, lane = tid & 63, wid = tid >> 6;
    int l15 = lane & 15, quad = lane >> 4;
    int wm = wid >> 1, wn = wid & 1;
    int m0 = blockIdx.y * 128, n0 = blockIdx.x * 128;

    int srow = tid >> 3;
    int sc8 = (((tid & 7) ^ (srow & 7)) * 8);
    const bf16_t* ga = &A[(size_t)(m0 + srow) * K + sc8];
    const bf16_t* gb = &Bt[(size_t)(n0 + srow) * K + sc8];
    bf16_t* la = &sA[(size_t)(wid * 64) * 8];
    bf16_t* lb = &sB[(size_t)(wid * 64) * 8];
    const size_t rstep = (size_t)32 * K;
    int x7 = l15 & 7;

    // B-fragment rows: pair cols (c, c+64) into adjacent j
    int jrow[4];
#pragma unroll
    for (int j = 0; j < 4; ++j)
        jrow[j] = (j & 1) * 64 + wn * 32 + (j >> 1) * 16 + l15;

    floatx4 acc[4][4] = {};
    for (int kk = 0; kk < K; kk += 64) {
#pragma unroll
        for (int l = 0; l < 4; ++l)
            gload_lds16(ga + l * rstep + kk, la + l * 2048);
#pragma unroll
        for (int l = 0; l < 4; ++l)
            gload_lds16(gb + l * rstep + kk, lb + l * 2048);
        __syncthreads();
#pragma unroll
        for (int k2 = 0; k2 < 2; ++k2) {
            int koff = ((k2 * 4 + quad) ^ x7) * 8;
            bf16x8 af[4], bfv[4];
#pragma unroll
            for (int i = 0; i < 4; ++i)
                af[i] = *(const bf16x8*)&sA[(wm * 64 + i * 16 + l15) * 64 + koff];
#pragma unroll
            for (int j = 0; j < 4; ++j)
                bfv[j] = *(const bf16x8*)&sB[jrow[j] * 64 + koff];
#pragma unroll
            for (int i = 0; i < 4; ++i)
#pragma unroll
                for (int j = 0; j < 4; ++j)
                    acc[i][j] = MFMA16(af[i], bfv[j], acc[i][j]);
        }
        __syncthreads();
    }

    if (z < 2) {
        // ---- fused RoPE epilogue (q: scaled, k: unscaled)
        float scale = (z == 0) ? 0.08838834764831845f : 1.0f;
#pragma unroll
        for (int jj = 0; jj < 2; ++jj) {
            int c = wn * 32 + jj * 16 + l15;                     // [0,64)
            float inv = exp2f(-(float)c * (13.287712379549449f / 64.f));
#pragma unroll
            for (int i = 0; i < 4; ++i)
#pragma unroll
                for (int r = 0; r < 4; ++r) {
                    int row = m0 + wm * 64 + i * 16 + quad * 4 + r;
                    float ang = (float)(row & 2047) * inv;
                    float sn, cs;
                    __sincosf(ang, &sn, &cs);
                    float x1 = acc[i][2 * jj][r], x2 = acc[i][2 * jj + 1][r];
                    size_t ro = (size_t)row * N + n0 + c;
                    C[ro]      = (bf16_t)((x1 * cs - x2 * sn) * scale);
                    C[ro + 64] = (bf16_t)((x2 * cs + x1 * sn) * scale);
                }
        }
    } else {
#pragma unroll
        for (int i = 0; i < 4; ++i)
#pragma unroll
            for (int j = 0; j < 4; ++j)
#pragma unroll
                for (int r = 0; r < 4; ++r) {
                    int row = m0 + wm * 64 + i * 16 + quad * 4 + r;
                    int col = n0 + jrow[j];
                    C[(size_t)row * N + col] = (bf16_t)acc[i][j][r];
                }
    }
}

// ---------------------------------------------------------------------------
// Final GEMM: out dtype dynamic (flag=1 -> bf16, else fp32).
// ---------------------------------------------------------------------------
__global__ __launch_bounds__(256) void gemm_bt_dyn(const bf16_t* __restrict__ A,
                                                   const bf16_t* __restrict__ Bt,
                                                   void* __restrict__ C, int K,
                                                   const int* __restrict__ flag) {
    __shared__ bf16_t sA[128 * 64];
    __shared__ bf16_t sB[128 * 64];
    const int N = 2048;
    int tid = threadIdx.x, lane = tid & 63, wid = tid >> 6;
    int l15 = lane & 15, quad = lane >> 4;
    int wm = wid >> 1, wn = wid & 1;
    int m0 = blockIdx.y * 128, n0 = blockIdx.x * 128;
    int isbf = *flag;

    int srow = tid >> 3;
    int sc8 = (((tid & 7) ^ (srow & 7)) * 8);
    const bf16_t* ga = &A[(size_t)(m0 + srow) * K + sc8];
    const bf16_t* gb = &Bt[(size_t)(n0 + srow) * K + sc8];
    bf16_t* la = &sA[(size_t)(wid * 64) * 8];
    bf16_t* lb = &sB[(size_t)(wid * 64) * 8];
    const size_t rstep = (size_t)32 * K;
    int x7 = l15 & 7;

    floatx4 acc[4][4] = {};
    for (int kk = 0; kk < K; kk += 64) {
#pragma unroll
        for (int l = 0; l < 4; ++l)
            gload_lds16(ga + l * rstep + kk, la + l * 2048);
#pragma unroll
        for (int l = 0; l < 4; ++l)
            gload_lds16(gb + l * rstep + kk, lb + l * 2048);
        __syncthreads();
#pragma unroll
        for (int k2 = 0; k2 < 2; ++k2) {
            int koff = ((k2 * 4 + quad) ^ x7) * 8;
            bf16x8 af[4], bfv[4];
#pragma unroll
            for (int i = 0; i < 4; ++i)
                af[i] = *(const bf16x8*)&sA[(wm * 64 + i * 16 + l15) * 64 + koff];
#pragma unroll
            for (int j = 0; j < 4; ++j)
                bfv[j] = *(const bf16x8*)&sB[(wn * 64 + j * 16 + l15) * 64 + koff];
#pragma unroll
            for (int i = 0; i < 4; ++i)
#pragma unroll
                for (int j = 0; j < 4; ++j)
                    acc[i][j] = MFMA16(af[i], bfv[j], acc[i][j]);
        }
        __syncthreads();
    }
#pragma unroll
    for (int i = 0; i < 4; ++i)
#pragma unroll
        for (int j = 0; j < 4; ++j)
#pragma unroll
            for (int r = 0; r < 4; ++r) {
                int row = m0 + wm * 64 + i * 16 + quad * 4 + r;
                int col = n0 + wn * 64 + j * 16 + l15;
                if (isbf) ((bf16_t*)C)[(size_t)row * N + col] = (bf16_t)acc[i][j][r];
                else      ((float*)C)[(size_t)row * N + col] = acc[i][j][r];
            }
}

// ---------------------------------------------------------------------------
// Pass A: Ut[e][d] = sum_t v[t][e] * gamma^(63-t) * k[t][d].  grid 1024.
// Transposed staging uses column-chunk XOR swizzle, key (e>>3)&7:
// element (row e, col t) at col' = (t&7) + 8*((t>>3) ^ ((e>>3)&7)).
// Writes: 16 k-lanes spread over 8 bank groups (was 16-way conflict).
// ---------------------------------------------------------------------------
__global__ __launch_bounds__(256) void chunk_state_kernel(const bf16_t* __restrict__ Kc,
                                                          const bf16_t* __restrict__ Vc,
                                                          bf16_t* __restrict__ U) {
    __shared__ bf16_t sKT[128 * 72];
    __shared__ bf16_t sVT[128 * 72];
    int bx = blockIdx.x;
    int n = bx & 31, h = (bx >> 5) & 15, b = bx >> 9;
    int tid = threadIdx.x, lane = tid & 63, wid = tid >> 6;
    int l15 = lane & 15, quad = lane >> 4;
    int wm = wid >> 1, wn = wid & 1;
    float log2g = log2f(1.f - exp2f(-5.f - (float)h));

#pragma unroll
    for (int l = 0; l < 4; ++l) {
        int idx = tid + 256 * l;          // 1024 = 64 rows x 16 vec8
        int t = idx >> 4, k = idx & 15, d8 = k * 8;
        size_t gb = (((size_t)((b * 2048 + n * 64 + t) * 16 + h)) << 7) + d8;
        bf16x8 kv = *(const bf16x8*)&Kc[gb];
        bf16x8 vv = *(const bf16x8*)&Vc[gb];
        float kdec = exp2f((float)(63 - t) * log2g);
        int swc = (((t >> 3) ^ (k & 7)) * 8) + (t & 7);
#pragma unroll
        for (int m = 0; m < 8; ++m) {
            sKT[(d8 + m) * 72 + swc] = (bf16_t)((float)kv[m] * kdec);
            sVT[(d8 + m) * 72 + swc] = vv[m];
        }
    }
    __syncthreads();

    floatx4 acc[4][4] = {};
#pragma unroll
    for (int k2 = 0; k2 < 2; ++k2) {
        int q = k2 * 4 + quad;
        bf16x8 af[4], bfv[4];
#pragma unroll
        for (int i = 0; i < 4; ++i) {
            int key = (2 * i + (l15 >> 3)) & 7;
            af[i] = *(const bf16x8*)&sVT[(wm * 64 + i * 16 + l15) * 72 + (q ^ key) * 8];
        }
#pragma unroll
        for (int j = 0; j < 4; ++j) {
            int key = (2 * j + (l15 >> 3)) & 7;
            bfv[j] = *(const bf16x8*)&sKT[(wn * 64 + j * 16 + l15) * 72 + (q ^ key) * 8];
        }
#pragma unroll
        for (int i = 0; i < 4; ++i)
#pragma unroll
            for (int j = 0; j < 4; ++j) acc[i][j] = MFMA16(af[i], bfv[j], acc[i][j]);
    }
    size_t ub = (size_t)bx * 16384;
#pragma unroll
    for (int i = 0; i < 4; ++i)
#pragma unroll
        for (int j = 0; j < 4; ++j)
#pragma unroll
            for (int r = 0; r < 4; ++r) {
                int e = wm * 64 + i * 16 + quad * 4 + r;
                int d = wn * 64 + j * 16 + l15;
                U[ub + (size_t)e * 128 + d] = (bf16_t)acc[i][j][r];
            }
}

// ---------------------------------------------------------------------------
// Pass B: in-place scan  St[n] = state before chunk n (transposed layout).
// ---------------------------------------------------------------------------
__global__ __launch_bounds__(256) void scan_kernel(bf16_t* __restrict__ US) {
    int bx = blockIdx.x;
    int bh = bx >> 3, slice = bx & 7;
    int h = bh & 15;
    float log2g = log2f(1.f - exp2f(-5.f - (float)h));
    float gC = exp2f(64.f * log2g);
    size_t base = (size_t)bh * 32 * 16384 + (size_t)slice * 2048 + (size_t)threadIdx.x * 8;
    float acc[8] = {};
#pragma unroll 4
    for (int n = 0; n < 32; ++n) {
        size_t o = base + (size_t)n * 16384;
        bf16x8 u = *(const bf16x8*)&US[o];
        bf16x8 s;
#pragma unroll
        for (int m = 0; m < 8; ++m) s[m] = (bf16_t)acc[m];
        *(bf16x8*)&US[o] = s;
#pragma unroll
        for (int m = 0; m < 8; ++m) acc[m] = gC * acc[m] + (float)u[m];
    }
}

// ---------------------------------------------------------------------------
// Pass C: chunk output + gated RMSNorm.  grid 1024.
// sQ/sK: [64][128] with chunk XOR swizzle key (t&7)  (16 KB each, no pad).
// sVT:   [128][72] chunk_state-style swizzle key (e>>3)&7.
// sA overlays sK (dead after phase 1)  -> ~51 KB LDS -> 3 blocks/CU.
// ---------------------------------------------------------------------------
__global__ __launch_bounds__(256) void chunk_out_kernel(
    const bf16_t* __restrict__ Q, const bf16_t* __restrict__ Kc,
    const bf16_t* __restrict__ Vc, const bf16_t* __restrict__ G,
    const void* __restrict__ gwp, const bf16_t* __restrict__ St,
    bf16_t* __restrict__ OG, const int* __restrict__ flag) {
    __shared__ bf16_t sQ[64 * 128];
    __shared__ bf16_t sKA[64 * 128];   // sK (swizzled) in phase 1; sA [64][72] in phase 2
    __shared__ bf16_t sVT[128 * 72];
    __shared__ float sgw[128];
    bf16_t* sA = sKA;
    int bx = blockIdx.x;
    int n = bx & 31, h = (bx >> 5) & 15, b = bx >> 9;
    int tid = threadIdx.x, lane = tid & 63, wid = tid >> 6;
    int l15 = lane & 15, quad = lane >> 4;
    float log2g = log2f(1.f - exp2f(-5.f - (float)h));

    if (tid < 128) {
        sgw[tid] = (*flag) ? (float)((const bf16_t*)gwp)[tid] : ((const float*)gwp)[tid];
    }
#pragma unroll
    for (int l = 0; l < 4; ++l) {
        int idx = tid + 256 * l;
        int t = idx >> 4, k = idx & 15, d8 = k * 8;
        size_t gb = (((size_t)((b * 2048 + n * 64 + t) * 16 + h)) << 7) + d8;
        int qk_off = t * 128 + ((k ^ (t & 7)) * 8);       // chunk swizzle key (t&7)
        *(bf16x8*)&sQ[qk_off] = *(const bf16x8*)&Q[gb];
        *(bf16x8*)&sKA[qk_off] = *(const bf16x8*)&Kc[gb];
        bf16x8 vv = *(const bf16x8*)&Vc[gb];
        int swc = (((t >> 3) ^ (k & 7)) * 8) + (t & 7);   // sVT swizzle key (e>>3)&7
#pragma unroll
        for (int m = 0; m < 8; ++m) sVT[(d8 + m) * 72 + swc] = vv[m];
    }
    __syncthreads();

    // ---- phase 1: A = q k^T (64x64), decay mask
    int t0 = wid * 16;
    int x7 = l15 & 7;
    floatx4 accA[4] = {};
#pragma unroll
    for (int kk = 0; kk < 4; ++kk) {
        int qd = kk * 4 + quad;
        bf16x8 aq = *(const bf16x8*)&sQ[(t0 + l15) * 128 + (qd ^ x7) * 8];
#pragma unroll
        for (int j = 0; j < 4; ++j) {
            bf16x8 bk = *(const bf16x8*)&sKA[(j * 16 + l15) * 128 + (qd ^ x7) * 8];
            accA[j] = MFMA16(aq, bk, accA[j]);
        }
    }
    __syncthreads();                      // sK consumed; sA may now overwrite it
#pragma unroll
    for (int j = 0; j < 4; ++j)
#pragma unroll
        for (int r = 0; r < 4; ++r) {
            int t = t0 + quad * 4 + r;
            int s = j * 16 + l15;
            int rel = t - s;
            float v = (rel >= 0) ? accA[j][r] * exp2f((float)rel * log2g) : 0.f;
            sA[t * 72 + s] = (bf16_t)v;
        }
    __syncthreads();

    // ---- phase 2: o = A v + (q*cross) S
    floatx4 acc[8] = {};
#pragma unroll
    for (int kk = 0; kk < 2; ++kk) {          // K = 64 (s)
        int s0 = kk * 32 + quad * 8;
        int qs = kk * 4 + quad;
        bf16x8 aa = *(const bf16x8*)&sA[(t0 + l15) * 72 + s0];
#pragma unroll
        for (int j = 0; j < 8; ++j) {
            int key = (2 * j + (l15 >> 3)) & 7;
            bf16x8 bv = *(const bf16x8*)&sVT[(j * 16 + l15) * 72 + (qs ^ key) * 8];
            acc[j] = MFMA16(aa, bv, acc[j]);
        }
    }
    size_t sb = (size_t)bx * 16384;
    float crossf = exp2f((float)(t0 + l15 + 1) * log2g);
#pragma unroll
    for (int kk = 0; kk < 4; ++kk) {          // K = 128 (d)
        int qd = kk * 4 + quad;
        bf16x8 aq = *(const bf16x8*)&sQ[(t0 + l15) * 128 + (qd ^ x7) * 8];
        bf16x8 aqs;
#pragma unroll
        for (int m = 0; m < 8; ++m) aqs[m] = (bf16_t)((float)aq[m] * crossf);
        int d0 = kk * 32 + quad * 8;
#pragma unroll
        for (int j = 0; j < 8; ++j) {
            bf16x8 bs = *(const bf16x8*)&St[sb + (size_t)(j * 16 + l15) * 128 + d0];
            acc[j] = MFMA16(aqs, bs, acc[j]);
        }
    }

    // ---- epilogue: gated RMSNorm per row t
#pragma unroll
    for (int r = 0; r < 4; ++r) {
        float ss = 0.f;
#pragma unroll
        for (int j = 0; j < 8; ++j) ss += acc[j][r] * acc[j][r];
        ss += __shfl_xor(ss, 1);
        ss += __shfl_xor(ss, 2);
        ss += __shfl_xor(ss, 4);
        ss += __shfl_xor(ss, 8);
        float rms = rsqrtf(ss * (1.f / 128.f) + 1e-5f);
        int t = t0 + quad * 4 + r;
        size_t gb = ((size_t)((b * 2048 + n * 64 + t) * 16 + h)) << 7;
#pragma unroll
        for (int j = 0; j < 8; ++j) {
            int e = j * 16 + l15;
            float g_ = (float)G[gb + e];
            float sw = g_ / (1.f + __expf(-g_));
            OG[gb + e] = (bf16_t)(acc[j][r] * rms * sgw[e] * sw);
        }
    }
}

// ---------------------------------------------------------------------------
extern "C" void kernel_launch(void* const* d_in, const int* in_sizes, int n_in,
                              void* d_out, int out_size, void* d_ws, size_t ws_size,
                              hipStream_t stream) {
    char* ws = (char*)d_ws;
    const size_t WBYTES = 2048ull * 2048 * 2;   // 8 MiB per bf16 weight
    const size_t ABYTES = 4096ull * 2048 * 2;   // 16 MiB per bf16 activation
    int* flag = (int*)ws;
    char* base = ws + 256;
    bf16_t* xb = (bf16_t*)base;
    bf16_t* WT[5];
    for (int i = 0; i < 5; ++i) WT[i] = (bf16_t*)(base + ABYTES + i * WBYTES);
    char* act = base + ABYTES + 5 * WBYTES;
    bf16_t* qb = (bf16_t*)(act + 0 * ABYTES);
    bf16_t* kb = (bf16_t*)(act + 1 * ABYTES);
    bf16_t* vb = (bf16_t*)(act + 2 * ABYTES);
    bf16_t* gb = (bf16_t*)(act + 3 * ABYTES);
    bf16_t* og = (bf16_t*)(act + 4 * ABYTES);
    bf16_t* US = (bf16_t*)(act + 5 * ABYTES);  // 32 MiB

    // 0. detect dtype (flag=1 -> bf16 inputs)
    detect_dtype_kernel<<<1, 256, 0, stream>>>((const unsigned int*)d_in[1], flag);

    // 1. canonicalize x; transpose+canonicalize all 5 weights
    convert_x_kernel<<<4096, 256, 0, stream>>>(d_in[0], xb, flag);
    TPtrs tp;
    tp.src[0] = d_in[1]; tp.src[1] = d_in[2]; tp.src[2] = d_in[3];
    tp.src[3] = d_in[4]; tp.src[4] = d_in[6];
    for (int i = 0; i < 5; ++i) tp.dst[i] = WT[i];
    transpose_k<<<dim3(32, 32, 5), 256, 0, stream>>>(tp, flag);

    // 2. fused QKVG projections with fused RoPE (z=0: q scaled, z=1: k)
    GPtrs gp;
    gp.Bt[0] = WT[0]; gp.Bt[1] = WT[1]; gp.Bt[2] = WT[2]; gp.Bt[3] = WT[3];
    gp.C[0] = qb; gp.C[1] = kb; gp.C[2] = vb; gp.C[3] = gb;
    gemm_bt<<<dim3(16, 32, 4), 256, 0, stream>>>(xb, gp, 2048);

    // 3. retention
    chunk_state_kernel<<<1024, 256, 0, stream>>>(kb, vb, US);
    scan_kernel<<<256, 256, 0, stream>>>(US);
    chunk_out_kernel<<<1024, 256, 0, stream>>>(qb, kb, vb, gb, d_in[5], US, og, flag);

    // 4. output projection (dtype-dynamic store)
    gemm_bt_dyn<<<dim3(16, 32, 1), 256, 0, stream>>>(og, WT[4], d_out, 2048, flag);
}

// Round 7
// 420.740 us; speedup vs baseline: 1.1642x; 1.0020x over previous
//
#include <hip/hip_runtime.h>

typedef __bf16 bf16_t;
typedef __bf16 bf16x8 __attribute__((ext_vector_type(8)));
typedef float floatx4 __attribute__((ext_vector_type(4)));

#define MFMA16(a, b, c) __builtin_amdgcn_mfma_f32_16x16x32_bf16(a, b, c, 0, 0, 0)

#define AS1 __attribute__((address_space(1)))
#define AS3 __attribute__((address_space(3)))

// async 16B global -> LDS (lane i lands at ldsbase + i*16; ldsbase wave-uniform)
__device__ __forceinline__ void gload_lds16(const bf16_t* g, bf16_t* l) {
    __builtin_amdgcn_global_load_lds((const AS1 unsigned int*)g,
                                     (AS3 unsigned int*)l, 16, 0, 0);
}

struct TPtrs { const void* src[5]; bf16_t* dst[5]; };
struct GPtrs { const bf16_t* Bt[4]; bf16_t* C[4]; };

// ---------------------------------------------------------------------------
// Detect input dtype on-device (flag=1 -> bf16 inputs; measured: fp32 world).
// ---------------------------------------------------------------------------
__global__ __launch_bounds__(256) void detect_dtype_kernel(const unsigned int* W,
                                                           int* flag) {
    int tid = threadIdx.x;
    int cnt = 0;
    for (int i = tid; i < 4096; i += 256) {
        unsigned int fb = (W[i] & 0xFFFFu) << 16;
        float v = __uint_as_float(fb);
        float a = fabsf(v);
        if (a > 1e-5f && a < 4.f) cnt++;
    }
    __shared__ int s[256];
    s[tid] = cnt;
    __syncthreads();
    for (int st = 128; st > 0; st >>= 1) {
        if (tid < st) s[tid] += s[tid + st];
        __syncthreads();
    }
    if (tid == 0) *flag = (s[0] > 2048) ? 1 : 0;
}

// ---------------------------------------------------------------------------
// Fused prep: z<5 -> transpose weight z (2048x2048 -> bf16, dst[n][k]);
// z==5 -> canonicalize x -> bf16 (8,388,608 elems).  grid (32,32,6).
// ---------------------------------------------------------------------------
__global__ __launch_bounds__(256) void prep_kernel(TPtrs p,
                                                   const void* __restrict__ xsrc,
                                                   bf16_t* __restrict__ xb,
                                                   const int* __restrict__ flag) {
    int z = blockIdx.z;
    int tid = threadIdx.x;
    int isbf = *flag;
    if (z == 5) {
        size_t blin = (size_t)blockIdx.y * 32 + blockIdx.x;   // [0,1024)
        size_t i0 = (blin * 256 + tid) * 8;
#pragma unroll
        for (int l = 0; l < 4; ++l) {
            size_t idx = i0 + (size_t)l * 2097152;            // 1024*256*8
            bf16x8 o;
            if (isbf) {
                o = *(const bf16x8*)((const bf16_t*)xsrc + idx);
            } else {
                const float* s = (const float*)xsrc + idx;
                float4 a = *(const float4*)s;
                float4 b = *(const float4*)(s + 4);
                o[0] = (bf16_t)a.x; o[1] = (bf16_t)a.y; o[2] = (bf16_t)a.z; o[3] = (bf16_t)a.w;
                o[4] = (bf16_t)b.x; o[5] = (bf16_t)b.y; o[6] = (bf16_t)b.z; o[7] = (bf16_t)b.w;
            }
            *(bf16x8*)(xb + idx) = o;
        }
        return;
    }
    __shared__ bf16_t tile[64][72];  // +8 pad
    bf16_t* dst = p.dst[z];
    int bx = blockIdx.x, by = blockIdx.y;
#pragma unroll
    for (int l = 0; l < 2; ++l) {
        int idx = tid + 256 * l;          // 512 x 8 elems = 64 rows x 64 cols
        int r = idx >> 3, c8 = (idx & 7) * 8;
        bf16x8 o;
        if (isbf) {
            const bf16_t* src = (const bf16_t*)p.src[z];
            o = *(const bf16x8*)&src[(size_t)(by * 64 + r) * 2048 + bx * 64 + c8];
        } else {
            const float* src = (const float*)p.src[z];
            const float* sp = &src[(size_t)(by * 64 + r) * 2048 + bx * 64 + c8];
            float4 a = *(const float4*)sp;
            float4 b = *(const float4*)(sp + 4);
            o[0] = (bf16_t)a.x; o[1] = (bf16_t)a.y; o[2] = (bf16_t)a.z; o[3] = (bf16_t)a.w;
            o[4] = (bf16_t)b.x; o[5] = (bf16_t)b.y; o[6] = (bf16_t)b.z; o[7] = (bf16_t)b.w;
        }
        *(bf16x8*)&tile[r][c8] = o;
    }
    __syncthreads();
#pragma unroll
    for (int l = 0; l < 2; ++l) {
        int idx = tid + 256 * l;
        int r = idx >> 3, c8 = (idx & 7) * 8;
        bf16x8 o;
#pragma unroll
        for (int m = 0; m < 8; ++m) o[m] = tile[c8 + m][r];
        *(bf16x8*)&dst[(size_t)(bx * 64 + r) * 2048 + by * 64 + c8] = o;
    }
}

// ---------------------------------------------------------------------------
// QKVG GEMM with fused RoPE.  C[M,N] = A[M,K] @ Bt[N,K]^T, bf16 out.
// m97 staging + XOR swizzle (conflict-free).  Staging addresses are
// uniform-base + 32-bit lane offset to get saddr-form global_load_lds
// (0 VALU per load; scalar pointer advance per K-step).
// ---------------------------------------------------------------------------
__global__ __launch_bounds__(256) void gemm_bt(const bf16_t* __restrict__ A, GPtrs p,
                                               int K) {
    __shared__ bf16_t sA[128 * 64];
    __shared__ bf16_t sB[128 * 64];
    int z = blockIdx.z;
    bf16_t* __restrict__ C = p.C[z];
    const int N = 2048;
    int tid = threadIdx.x, lane = tid & 63, wid = tid >> 6;
    int l15 = lane & 15, quad = lane >> 4;
    int wm = wid >> 1, wn = wid & 1;
    int m0 = blockIdx.y * 128, n0 = blockIdx.x * 128;

    int srow = tid >> 3;
    unsigned aoff = (unsigned)(srow * K + (((tid & 7) ^ (srow & 7)) * 8));
    const bf16_t* Au = A + (size_t)m0 * K;          // uniform
    const bf16_t* Bu = p.Bt[z] + (size_t)n0 * K;    // uniform
    bf16_t* la = &sA[(size_t)(wid * 64) * 8];
    bf16_t* lb = &sB[(size_t)(wid * 64) * 8];
    const int rstep = 32 * K;                        // uniform, elems
    int x7 = l15 & 7;

    // B-fragment rows: pair cols (c, c+64) into adjacent j
    int jrow[4];
#pragma unroll
    for (int j = 0; j < 4; ++j)
        jrow[j] = (j & 1) * 64 + wn * 32 + (j >> 1) * 16 + l15;

    floatx4 acc[4][4] = {};
    for (int kk = 0; kk < K; kk += 64) {
#pragma unroll
        for (int l = 0; l < 4; ++l)
            gload_lds16(Au + l * rstep + aoff, la + l * 2048);
#pragma unroll
        for (int l = 0; l < 4; ++l)
            gload_lds16(Bu + l * rstep + aoff, lb + l * 2048);
        Au += 64;
        Bu += 64;
        __syncthreads();
#pragma unroll
        for (int k2 = 0; k2 < 2; ++k2) {
            int koff = ((k2 * 4 + quad) ^ x7) * 8;
            bf16x8 af[4], bfv[4];
#pragma unroll
            for (int i = 0; i < 4; ++i)
                af[i] = *(const bf16x8*)&sA[(wm * 64 + i * 16 + l15) * 64 + koff];
#pragma unroll
            for (int j = 0; j < 4; ++j)
                bfv[j] = *(const bf16x8*)&sB[jrow[j] * 64 + koff];
#pragma unroll
            for (int i = 0; i < 4; ++i)
#pragma unroll
                for (int j = 0; j < 4; ++j)
                    acc[i][j] = MFMA16(af[i], bfv[j], acc[i][j]);
        }
        __syncthreads();
    }

    if (z < 2) {
        // ---- fused RoPE epilogue (q: scaled, k: unscaled)
        float scale = (z == 0) ? 0.08838834764831845f : 1.0f;
#pragma unroll
        for (int jj = 0; jj < 2; ++jj) {
            int c = wn * 32 + jj * 16 + l15;                     // [0,64)
            float inv = exp2f(-(float)c * (13.287712379549449f / 64.f));
#pragma unroll
            for (int i = 0; i < 4; ++i)
#pragma unroll
                for (int r = 0; r < 4; ++r) {
                    int row = m0 + wm * 64 + i * 16 + quad * 4 + r;
                    float ang = (float)(row & 2047) * inv;
                    float sn, cs;
                    __sincosf(ang, &sn, &cs);
                    float x1 = acc[i][2 * jj][r], x2 = acc[i][2 * jj + 1][r];
                    size_t ro = (size_t)row * N + n0 + c;
                    C[ro]      = (bf16_t)((x1 * cs - x2 * sn) * scale);
                    C[ro + 64] = (bf16_t)((x2 * cs + x1 * sn) * scale);
                }
        }
    } else {
#pragma unroll
        for (int i = 0; i < 4; ++i)
#pragma unroll
            for (int j = 0; j < 4; ++j)
#pragma unroll
                for (int r = 0; r < 4; ++r) {
                    int row = m0 + wm * 64 + i * 16 + quad * 4 + r;
                    int col = n0 + jrow[j];
                    C[(size_t)row * N + col] = (bf16_t)acc[i][j][r];
                }
    }
}

// ---------------------------------------------------------------------------
// Final GEMM: out dtype dynamic (flag=1 -> bf16, else fp32).  saddr staging.
// ---------------------------------------------------------------------------
__global__ __launch_bounds__(256) void gemm_bt_dyn(const bf16_t* __restrict__ A,
                                                   const bf16_t* __restrict__ Bt,
                                                   void* __restrict__ C, int K,
                                                   const int* __restrict__ flag) {
    __shared__ bf16_t sA[128 * 64];
    __shared__ bf16_t sB[128 * 64];
    const int N = 2048;
    int tid = threadIdx.x, lane = tid & 63, wid = tid >> 6;
    int l15 = lane & 15, quad = lane >> 4;
    int wm = wid >> 1, wn = wid & 1;
    int m0 = blockIdx.y * 128, n0 = blockIdx.x * 128;
    int isbf = *flag;

    int srow = tid >> 3;
    unsigned aoff = (unsigned)(srow * K + (((tid & 7) ^ (srow & 7)) * 8));
    const bf16_t* Au = A + (size_t)m0 * K;
    const bf16_t* Bu = Bt + (size_t)n0 * K;
    bf16_t* la = &sA[(size_t)(wid * 64) * 8];
    bf16_t* lb = &sB[(size_t)(wid * 64) * 8];
    const int rstep = 32 * K;
    int x7 = l15 & 7;

    floatx4 acc[4][4] = {};
    for (int kk = 0; kk < K; kk += 64) {
#pragma unroll
        for (int l = 0; l < 4; ++l)
            gload_lds16(Au + l * rstep + aoff, la + l * 2048);
#pragma unroll
        for (int l = 0; l < 4; ++l)
            gload_lds16(Bu + l * rstep + aoff, lb + l * 2048);
        Au += 64;
        Bu += 64;
        __syncthreads();
#pragma unroll
        for (int k2 = 0; k2 < 2; ++k2) {
            int koff = ((k2 * 4 + quad) ^ x7) * 8;
            bf16x8 af[4], bfv[4];
#pragma unroll
            for (int i = 0; i < 4; ++i)
                af[i] = *(const bf16x8*)&sA[(wm * 64 + i * 16 + l15) * 64 + koff];
#pragma unroll
            for (int j = 0; j < 4; ++j)
                bfv[j] = *(const bf16x8*)&sB[(wn * 64 + j * 16 + l15) * 64 + koff];
#pragma unroll
            for (int i = 0; i < 4; ++i)
#pragma unroll
                for (int j = 0; j < 4; ++j)
                    acc[i][j] = MFMA16(af[i], bfv[j], acc[i][j]);
        }
        __syncthreads();
    }
#pragma unroll
    for (int i = 0; i < 4; ++i)
#pragma unroll
        for (int j = 0; j < 4; ++j)
#pragma unroll
            for (int r = 0; r < 4; ++r) {
                int row = m0 + wm * 64 + i * 16 + quad * 4 + r;
                int col = n0 + wn * 64 + j * 16 + l15;
                if (isbf) ((bf16_t*)C)[(size_t)row * N + col] = (bf16_t)acc[i][j][r];
                else      ((float*)C)[(size_t)row * N + col] = acc[i][j][r];
            }
}

// ---------------------------------------------------------------------------
// Pass A: Ut[e][d] = sum_t v[t][e] * gamma^(63-t) * k[t][d].  grid 1024.
// Column-chunk XOR swizzle on transposed staging (conflict-reduced).
// ---------------------------------------------------------------------------
__global__ __launch_bounds__(256) void chunk_state_kernel(const bf16_t* __restrict__ Kc,
                                                          const bf16_t* __restrict__ Vc,
                                                          bf16_t* __restrict__ U) {
    __shared__ bf16_t sKT[128 * 72];
    __shared__ bf16_t sVT[128 * 72];
    int bx = blockIdx.x;
    int n = bx & 31, h = (bx >> 5) & 15, b = bx >> 9;
    int tid = threadIdx.x, lane = tid & 63, wid = tid >> 6;
    int l15 = lane & 15, quad = lane >> 4;
    int wm = wid >> 1, wn = wid & 1;
    float log2g = log2f(1.f - exp2f(-5.f - (float)h));

#pragma unroll
    for (int l = 0; l < 4; ++l) {
        int idx = tid + 256 * l;          // 1024 = 64 rows x 16 vec8
        int t = idx >> 4, k = idx & 15, d8 = k * 8;
        size_t gb = (((size_t)((b * 2048 + n * 64 + t) * 16 + h)) << 7) + d8;
        bf16x8 kv = *(const bf16x8*)&Kc[gb];
        bf16x8 vv = *(const bf16x8*)&Vc[gb];
        float kdec = exp2f((float)(63 - t) * log2g);
        int swc = (((t >> 3) ^ (k & 7)) * 8) + (t & 7);
#pragma unroll
        for (int m = 0; m < 8; ++m) {
            sKT[(d8 + m) * 72 + swc] = (bf16_t)((float)kv[m] * kdec);
            sVT[(d8 + m) * 72 + swc] = vv[m];
        }
    }
    __syncthreads();

    floatx4 acc[4][4] = {};
#pragma unroll
    for (int k2 = 0; k2 < 2; ++k2) {
        int q = k2 * 4 + quad;
        bf16x8 af[4], bfv[4];
#pragma unroll
        for (int i = 0; i < 4; ++i) {
            int key = (2 * i + (l15 >> 3)) & 7;
            af[i] = *(const bf16x8*)&sVT[(wm * 64 + i * 16 + l15) * 72 + (q ^ key) * 8];
        }
#pragma unroll
        for (int j = 0; j < 4; ++j) {
            int key = (2 * j + (l15 >> 3)) & 7;
            bfv[j] = *(const bf16x8*)&sKT[(wn * 64 + j * 16 + l15) * 72 + (q ^ key) * 8];
        }
#pragma unroll
        for (int i = 0; i < 4; ++i)
#pragma unroll
            for (int j = 0; j < 4; ++j) acc[i][j] = MFMA16(af[i], bfv[j], acc[i][j]);
    }
    size_t ub = (size_t)bx * 16384;
#pragma unroll
    for (int i = 0; i < 4; ++i)
#pragma unroll
        for (int j = 0; j < 4; ++j)
#pragma unroll
            for (int r = 0; r < 4; ++r) {
                int e = wm * 64 + i * 16 + quad * 4 + r;
                int d = wn * 64 + j * 16 + l15;
                U[ub + (size_t)e * 128 + d] = (bf16_t)acc[i][j][r];
            }
}

// ---------------------------------------------------------------------------
// Pass B: in-place scan  St[n] = state before chunk n (transposed layout).
// ---------------------------------------------------------------------------
__global__ __launch_bounds__(256) void scan_kernel(bf16_t* __restrict__ US) {
    int bx = blockIdx.x;
    int bh = bx >> 3, slice = bx & 7;
    int h = bh & 15;
    float log2g = log2f(1.f - exp2f(-5.f - (float)h));
    float gC = exp2f(64.f * log2g);
    size_t base = (size_t)bh * 32 * 16384 + (size_t)slice * 2048 + (size_t)threadIdx.x * 8;
    float acc[8] = {};
#pragma unroll 4
    for (int n = 0; n < 32; ++n) {
        size_t o = base + (size_t)n * 16384;
        bf16x8 u = *(const bf16x8*)&US[o];
        bf16x8 s;
#pragma unroll
        for (int m = 0; m < 8; ++m) s[m] = (bf16_t)acc[m];
        *(bf16x8*)&US[o] = s;
#pragma unroll
        for (int m = 0; m < 8; ++m) acc[m] = gC * acc[m] + (float)u[m];
    }
}

// ---------------------------------------------------------------------------
// Pass C: chunk output + gated RMSNorm.  grid 1024.
// sQ/sK: [64][128] chunk XOR swizzle key (t&7); sVT: [128][72] swizzled;
// sA overlays sK (dead after phase 1) -> ~51 KB LDS -> 3 blocks/CU.
// ---------------------------------------------------------------------------
__global__ __launch_bounds__(256) void chunk_out_kernel(
    const bf16_t* __restrict__ Q, const bf16_t* __restrict__ Kc,
    const bf16_t* __restrict__ Vc, const bf16_t* __restrict__ G,
    const void* __restrict__ gwp, const bf16_t* __restrict__ St,
    bf16_t* __restrict__ OG, const int* __restrict__ flag) {
    __shared__ bf16_t sQ[64 * 128];
    __shared__ bf16_t sKA[64 * 128];   // sK (swizzled) in phase 1; sA [64][72] in phase 2
    __shared__ bf16_t sVT[128 * 72];
    __shared__ float sgw[128];
    bf16_t* sA = sKA;
    int bx = blockIdx.x;
    int n = bx & 31, h = (bx >> 5) & 15, b = bx >> 9;
    int tid = threadIdx.x, lane = tid & 63, wid = tid >> 6;
    int l15 = lane & 15, quad = lane >> 4;
    float log2g = log2f(1.f - exp2f(-5.f - (float)h));

    if (tid < 128) {
        sgw[tid] = (*flag) ? (float)((const bf16_t*)gwp)[tid] : ((const float*)gwp)[tid];
    }
#pragma unroll
    for (int l = 0; l < 4; ++l) {
        int idx = tid + 256 * l;
        int t = idx >> 4, k = idx & 15, d8 = k * 8;
        size_t gb = (((size_t)((b * 2048 + n * 64 + t) * 16 + h)) << 7) + d8;
        int qk_off = t * 128 + ((k ^ (t & 7)) * 8);       // chunk swizzle key (t&7)
        *(bf16x8*)&sQ[qk_off] = *(const bf16x8*)&Q[gb];
        *(bf16x8*)&sKA[qk_off] = *(const bf16x8*)&Kc[gb];
        bf16x8 vv = *(const bf16x8*)&Vc[gb];
        int swc = (((t >> 3) ^ (k & 7)) * 8) + (t & 7);   // sVT swizzle key
#pragma unroll
        for (int m = 0; m < 8; ++m) sVT[(d8 + m) * 72 + swc] = vv[m];
    }
    __syncthreads();

    // ---- phase 1: A = q k^T (64x64), decay mask
    int t0 = wid * 16;
    int x7 = l15 & 7;
    floatx4 accA[4] = {};
#pragma unroll
    for (int kk = 0; kk < 4; ++kk) {
        int qd = kk * 4 + quad;
        bf16x8 aq = *(const bf16x8*)&sQ[(t0 + l15) * 128 + (qd ^ x7) * 8];
#pragma unroll
        for (int j = 0; j < 4; ++j) {
            bf16x8 bk = *(const bf16x8*)&sKA[(j * 16 + l15) * 128 + (qd ^ x7) * 8];
            accA[j] = MFMA16(aq, bk, accA[j]);
        }
    }
    __syncthreads();                      // sK consumed; sA may now overwrite it
#pragma unroll
    for (int j = 0; j < 4; ++j)
#pragma unroll
        for (int r = 0; r < 4; ++r) {
            int t = t0 + quad * 4 + r;
            int s = j * 16 + l15;
            int rel = t - s;
            float v = (rel >= 0) ? accA[j][r] * exp2f((float)rel * log2g) : 0.f;
            sA[t * 72 + s] = (bf16_t)v;
        }
    __syncthreads();

    // ---- phase 2: o = A v + (q*cross) S
    floatx4 acc[8] = {};
#pragma unroll
    for (int kk = 0; kk < 2; ++kk) {          // K = 64 (s)
        int s0 = kk * 32 + quad * 8;
        int qs = kk * 4 + quad;
        bf16x8 aa = *(const bf16x8*)&sA[(t0 + l15) * 72 + s0];
#pragma unroll
        for (int j = 0; j < 8; ++j) {
            int key = (2 * j + (l15 >> 3)) & 7;
            bf16x8 bv = *(const bf16x8*)&sVT[(j * 16 + l15) * 72 + (qs ^ key) * 8];
            acc[j] = MFMA16(aa, bv, acc[j]);
        }
    }
    size_t sb = (size_t)bx * 16384;
    float crossf = exp2f((float)(t0 + l15 + 1) * log2g);
#pragma unroll
    for (int kk = 0; kk < 4; ++kk) {          // K = 128 (d)
        int qd = kk * 4 + quad;
        bf16x8 aq = *(const bf16x8*)&sQ[(t0 + l15) * 128 + (qd ^ x7) * 8];
        bf16x8 aqs;
#pragma unroll
        for (int m = 0; m < 8; ++m) aqs[m] = (bf16_t)((float)aq[m] * crossf);
        int d0 = kk * 32 + quad * 8;
#pragma unroll
        for (int j = 0; j < 8; ++j) {
            bf16x8 bs = *(const bf16x8*)&St[sb + (size_t)(j * 16 + l15) * 128 + d0];
            acc[j] = MFMA16(aqs, bs, acc[j]);
        }
    }

    // ---- epilogue: gated RMSNorm per row t
#pragma unroll
    for (int r = 0; r < 4; ++r) {
        float ss = 0.f;
#pragma unroll
        for (int j = 0; j < 8; ++j) ss += acc[j][r] * acc[j][r];
        ss += __shfl_xor(ss, 1);
        ss += __shfl_xor(ss, 2);
        ss += __shfl_xor(ss, 4);
        ss += __shfl_xor(ss, 8);
        float rms = rsqrtf(ss * (1.f / 128.f) + 1e-5f);
        int t = t0 + quad * 4 + r;
        size_t gb = ((size_t)((b * 2048 + n * 64 + t) * 16 + h)) << 7;
#pragma unroll
        for (int j = 0; j < 8; ++j) {
            int e = j * 16 + l15;
            float g_ = (float)G[gb + e];
            float sw = g_ / (1.f + __expf(-g_));
            OG[gb + e] = (bf16_t)(acc[j][r] * rms * sgw[e] * sw);
        }
    }
}

// ---------------------------------------------------------------------------
extern "C" void kernel_launch(void* const* d_in, const int* in_sizes, int n_in,
                              void* d_out, int out_size, void* d_ws, size_t ws_size,
                              hipStream_t stream) {
    char* ws = (char*)d_ws;
    const size_t WBYTES = 2048ull * 2048 * 2;   // 8 MiB per bf16 weight
    const size_t ABYTES = 4096ull * 2048 * 2;   // 16 MiB per bf16 activation
    int* flag = (int*)ws;
    char* base = ws + 256;
    bf16_t* xb = (bf16_t*)base;
    bf16_t* WT[5];
    for (int i = 0; i < 5; ++i) WT[i] = (bf16_t*)(base + ABYTES + i * WBYTES);
    char* act = base + ABYTES + 5 * WBYTES;
    bf16_t* qb = (bf16_t*)(act + 0 * ABYTES);
    bf16_t* kb = (bf16_t*)(act + 1 * ABYTES);
    bf16_t* vb = (bf16_t*)(act + 2 * ABYTES);
    bf16_t* gb = (bf16_t*)(act + 3 * ABYTES);
    bf16_t* og = (bf16_t*)(act + 4 * ABYTES);
    bf16_t* US = (bf16_t*)(act + 5 * ABYTES);  // 32 MiB

    // 0. detect dtype (flag=1 -> bf16 inputs)
    detect_dtype_kernel<<<1, 256, 0, stream>>>((const unsigned int*)d_in[1], flag);

    // 1. fused prep: transpose 5 weights (z<5) + canonicalize x (z=5)
    TPtrs tp;
    tp.src[0] = d_in[1]; tp.src[1] = d_in[2]; tp.src[2] = d_in[3];
    tp.src[3] = d_in[4]; tp.src[4] = d_in[6];
    for (int i = 0; i < 5; ++i) tp.dst[i] = WT[i];
    prep_kernel<<<dim3(32, 32, 6), 256, 0, stream>>>(tp, d_in[0], xb, flag);

    // 2. fused QKVG projections with fused RoPE (z=0: q scaled, z=1: k)
    GPtrs gp;
    gp.Bt[0] = WT[0]; gp.Bt[1] = WT[1]; gp.Bt[2] = WT[2]; gp.Bt[3] = WT[3];
    gp.C[0] = qb; gp.C[1] = kb; gp.C[2] = vb; gp.C[3] = gb;
    gemm_bt<<<dim3(16, 32, 4), 256, 0, stream>>>(xb, gp, 2048);

    // 3. retention
    chunk_state_kernel<<<1024, 256, 0, stream>>>(kb, vb, US);
    scan_kernel<<<256, 256, 0, stream>>>(US);
    chunk_out_kernel<<<1024, 256, 0, stream>>>(qb, kb, vb, gb, d_in[5], US, og, flag);

    // 4. output projection (dtype-dynamic store)
    gemm_bt_dyn<<<dim3(16, 32, 1), 256, 0, stream>>>(og, WT[4], d_out, 2048, flag);
}